// Round 8
// baseline (973.910 us; speedup 1.0000x reference)
//
#include <hip/hip_runtime.h>
#include <float.h>
#include <math.h>

#define BCLOUDS 16
#define PPTS    1024
#define NPTS    (BCLOUDS * PPTS)
#define KNB     32
#define NCLS    40
#define RPB     8                  // rows per knn block (= waves per block)
#define NBIN    256
#define HROW    (NBIN + NBIN / 16) // padded words per row histogram
#define SELFM   0xFFFFFFFFu        // self marker: strictly above any real d2 bits (<=0x7F7FFFFF)
#define SENT    0xFFFFFFFFu        // pk sentinel for done rows

__device__ __forceinline__ int hidx(int b) { return b + (b >> 4); }

// ---------------------------------------------------------------------------
// kNN: block-cooperative radix select. 512 threads / 8 rows; thread owns
// candidates q=tid,tid+512 with distance bits in REGISTERS (no dmat).
// Per row: atomicMin/Max -> (base,shift); <=4 MSD-radix passes, each pass:
// 1 LDS atomicAdd per surviving candidate; wave r scans row r's 256 bins.
// shift==0 remainder = exact-value ties -> bitmap + prefix-popc picks R
// smallest indices (lax.top_k tie-break). Self provably unselectable.
// ---------------------------------------------------------------------------
template<int F>
__global__ __launch_bounds__(512, 6) void knn_kernel(const float* __restrict__ x,
                                                     int* __restrict__ nbr) {
    __shared__ float    xp[RPB][F];
    __shared__ float    rn[RPB];
    __shared__ unsigned hist[RPB][HROW];
    __shared__ unsigned rminS[RPB], rmaxS[RPB];
    __shared__ unsigned baseS[2][RPB]; __shared__ int shiftS[2][RPB];
    __shared__ unsigned pkS[RPB];
    __shared__ int      rRS[RPB], doneS[RPB];
    __shared__ unsigned bitmap[RPB][32];
    __shared__ unsigned slotS[RPB];
    __shared__ int      ndoneS;

    const int tid   = threadIdx.x;
    const int lane  = tid & 63;
    const int wave  = tid >> 6;            // 0..7
    const int bpc   = PPTS / RPB;
    const int cloud = blockIdx.x / bpc;
    const int pl0   = (blockIdx.x % bpc) * RPB;
    const float* xc = x + (size_t)cloud * PPTS * F;

    for (int i = tid; i < RPB * F; i += 512)
        xp[i / F][i % F] = xc[(size_t)(pl0 + i / F) * F + (i % F)];
    __syncthreads();
    if (tid < RPB) {
        float s = 0.f;
        for (int f = 0; f < F; ++f) { const float v = xp[tid][f]; s = fmaf(v, v, s); }
        rn[tid] = s;
    }
    __syncthreads();

    // ---- distances (identical numerics to prior passing rounds) ----
    float acc[RPB][2];
    float qnv[2];
#pragma unroll
    for (int c = 0; c < 2; ++c) qnv[c] = 0.f;
#pragma unroll
    for (int r = 0; r < RPB; ++r)
#pragma unroll
        for (int c = 0; c < 2; ++c) acc[r][c] = 0.f;

    if constexpr (F % 4 == 0) {
        const float4* xc4 = reinterpret_cast<const float4*>(xc);
#pragma unroll 2
        for (int f4 = 0; f4 < F / 4; ++f4) {
            float4 vq[2];
#pragma unroll
            for (int c = 0; c < 2; ++c) vq[c] = xc4[(size_t)(tid + c * 512) * (F / 4) + f4];
#pragma unroll
            for (int c = 0; c < 2; ++c) {
                qnv[c] = fmaf(vq[c].x, vq[c].x, qnv[c]);
                qnv[c] = fmaf(vq[c].y, vq[c].y, qnv[c]);
                qnv[c] = fmaf(vq[c].z, vq[c].z, qnv[c]);
                qnv[c] = fmaf(vq[c].w, vq[c].w, qnv[c]);
            }
            float4 xr[RPB];
#pragma unroll
            for (int r = 0; r < RPB; ++r) xr[r] = *reinterpret_cast<const float4*>(&xp[r][f4 * 4]);
#pragma unroll
            for (int r = 0; r < RPB; ++r)
#pragma unroll
                for (int c = 0; c < 2; ++c) {
                    acc[r][c] = fmaf(vq[c].x, xr[r].x, acc[r][c]);
                    acc[r][c] = fmaf(vq[c].y, xr[r].y, acc[r][c]);
                    acc[r][c] = fmaf(vq[c].z, xr[r].z, acc[r][c]);
                    acc[r][c] = fmaf(vq[c].w, xr[r].w, acc[r][c]);
                }
        }
    } else {
        for (int f = 0; f < F; ++f) {
            float vq[2];
#pragma unroll
            for (int c = 0; c < 2; ++c) vq[c] = xc[(size_t)(tid + c * 512) * F + f];
#pragma unroll
            for (int c = 0; c < 2; ++c) qnv[c] = fmaf(vq[c], vq[c], qnv[c]);
#pragma unroll
            for (int r = 0; r < RPB; ++r) {
                const float xv = xp[r][f];
#pragma unroll
                for (int c = 0; c < 2; ++c) acc[r][c] = fmaf(vq[c], xv, acc[r][c]);
            }
        }
    }
    unsigned bitsv[RPB][2];
#pragma unroll
    for (int c = 0; c < 2; ++c) {
        const int q = tid + c * 512;
#pragma unroll
        for (int r = 0; r < RPB; ++r) {
            float d2 = rn[r] + qnv[c] - 2.f * acc[r][c];
            d2 = fmaxf(d2, 0.f);
            bitsv[r][c] = (q == pl0 + r) ? SELFM : __float_as_uint(d2);
        }
    }

    // ---- init per-row state ----
    if (tid < RPB) {
        rminS[tid] = 0xFFFFFFFFu; rmaxS[tid] = 0u;
        rRS[tid] = KNB; doneS[tid] = 0; slotS[tid] = 0u;
    }
    if (tid == 0) ndoneS = 0;
    for (int i = tid; i < RPB * 32; i += 512) bitmap[i >> 5][i & 31] = 0u;
    __syncthreads();

    // ---- min/max atomics (self excluded from max) ----
#pragma unroll
    for (int r = 0; r < RPB; ++r) {
        const unsigned b0 = bitsv[r][0], b1 = bitsv[r][1];
        atomicMin(&rminS[r], min(b0, b1));
        const unsigned m0 = b0 == SELFM ? 0u : b0;
        const unsigned m1 = b1 == SELFM ? 0u : b1;
        atomicMax(&rmaxS[r], max(m0, m1));
    }
    __syncthreads();

    // ---- per-row base/shift prep + hist zero ----
    if (tid < RPB) {
        const unsigned mn = rminS[tid];
        const unsigned span = rmaxS[tid] - mn;   // rmax>=rmin (1023 reals)
        int sh = 0;
        if (span > 0) { const int lg = 31 - __clz(span); sh = lg > 7 ? lg - 7 : 0; }
        baseS[0][tid] = mn; shiftS[0][tid] = sh;
    }
    for (int i = tid; i < RPB * HROW; i += 512) hist[i / HROW][i % HROW] = 0u;
    __syncthreads();

    unsigned survm = 0xFFFFu;   // bit (r*2+c): still a candidate
    unsigned selm  = 0u;        // bit (r*2+c): definitively selected

#pragma unroll 1
    for (int pass = 0; pass < 4; ++pass) {
        const int cur = pass & 1, nxt = cur ^ 1;
        // ---- atomic phase ----
#pragma unroll
        for (int r = 0; r < RPB; ++r) {
            if (doneS[r] == 0) {
                const unsigned base = baseS[cur][r];
                const int sh = shiftS[cur][r];
#pragma unroll
                for (int c = 0; c < 2; ++c) {
                    if ((survm >> (r * 2 + c)) & 1) {
                        unsigned b = (bitsv[r][c] - base) >> sh;
                        b = b > 255u ? 255u : b;
                        atomicAdd(&hist[r][hidx((int)b)], 1u);
                    }
                }
            }
        }
        __syncthreads();
        // ---- scan phase: wave r owns row r ----
        {
            const int row = wave;
            if (doneS[row] != 0) {
                if (lane == 0) pkS[row] = SENT;
            } else {
                unsigned h[4];
                int cnt = 0;
#pragma unroll
                for (int j = 0; j < 4; ++j) { h[j] = hist[row][hidx(lane * 4 + j)]; cnt += (int)h[j]; }
                int inc = cnt;
#pragma unroll
                for (int off = 1; off < 64; off <<= 1) {
                    const int nv = __shfl_up(inc, off);
                    if (lane >= off) inc += nv;
                }
                const int pre = inc - cnt;
                const int R = rRS[row];
                if (pre < R && R <= inc) {         // exactly one lane
                    int c2 = pre, bb = -1, below = 0; unsigned hb = 0;
#pragma unroll
                    for (int j = 0; j < 4; ++j) {
                        if (bb < 0) {
                            if (c2 + (int)h[j] >= R) { bb = lane * 4 + j; hb = h[j]; below = c2; }
                            else c2 += (int)h[j];
                        }
                    }
                    const int need = R - below;    // 1..hb
                    const int sh = shiftS[cur][row];
                    int mode;
                    if ((int)hb == need && bb != 255) mode = 1;        // exact fit
                    else if (sh == 0) mode = 2;                        // exact ties remain
                    else mode = 0;                                     // refine
                    pkS[row] = (unsigned)bb | ((unsigned)mode << 10);
                    if (mode == 0) {
                        rRS[row] = need;
                        baseS[nxt][row] = baseS[cur][row] + ((unsigned)bb << sh);
                        shiftS[nxt][row] = sh > 8 ? sh - 8 : 0;
                    } else {
                        rRS[row] = need;           // used by tie pick (mode 2)
                        doneS[row] = mode;
                        atomicAdd(&ndoneS, 1);
                    }
                }
            }
        }
        __syncthreads();
        // ---- classify + re-zero hist ----
#pragma unroll
        for (int r = 0; r < RPB; ++r) {
            const unsigned pk = pkS[r];
            if (pk != SENT) {
                const int bb = (int)(pk & 1023u);
                const int mode = (int)((pk >> 10) & 3u);
                const unsigned base = baseS[cur][r];
                const int sh = shiftS[cur][r];
#pragma unroll
                for (int c = 0; c < 2; ++c) {
                    const int bit = r * 2 + c;
                    if ((survm >> bit) & 1) {
                        unsigned b = (bitsv[r][c] - base) >> sh;
                        b = b > 255u ? 255u : b;
                        if (mode == 1) {
                            if ((int)b <= bb) selm |= 1u << bit;
                            survm &= ~(1u << bit);
                        } else {
                            if ((int)b < bb) { selm |= 1u << bit; survm &= ~(1u << bit); }
                            else if ((int)b != bb) survm &= ~(1u << bit);
                            // b==bb: stays survivor (mode 0 refine or mode 2 tie)
                        }
                    }
                }
            }
        }
        for (int i = tid; i < RPB * HROW; i += 512) hist[i / HROW][i % HROW] = 0u;
        __syncthreads();
        if (ndoneS == RPB) break;   // uniform read post-sync
    }

    // ---- tie bitmap (rows with done==2) ----
#pragma unroll
    for (int r = 0; r < RPB; ++r) {
        if (doneS[r] == 2) {
#pragma unroll
            for (int c = 0; c < 2; ++c) {
                const int q = tid + c * 512;
                if (((survm >> (r * 2 + c)) & 1) && q != pl0 + r)
                    atomicOr(&bitmap[r][q >> 5], 1u << (q & 31));
            }
        }
    }
    __syncthreads();

    // ---- emit: selected candidates (unordered slots) ----
    int* outbase = nbr + (size_t)(cloud * PPTS + pl0) * KNB;
#pragma unroll
    for (int r = 0; r < RPB; ++r) {
#pragma unroll
        for (int c = 0; c < 2; ++c) {
            if ((selm >> (r * 2 + c)) & 1) {
                const int q = tid + c * 512;
                if (q != pl0 + r) {
                    const unsigned slot = atomicAdd(&slotS[r], 1u);
                    if (slot < KNB) outbase[(size_t)r * KNB + slot] = cloud * PPTS + q;
                }
            }
        }
    }
    // tie picks: wave r picks R smallest indices from bitmap
    {
        const int row = wave;
        if (doneS[row] == 2) {
            const int R = rRS[row];
            unsigned w = (lane < 32) ? bitmap[row][lane] : 0u;
            int cnt = __popc(w);
            int inc = cnt;
#pragma unroll
            for (int off = 1; off < 64; off <<= 1) {
                const int nv = __shfl_up(inc, off);
                if (lane >= off) inc += nv;
            }
            const int pre = inc - cnt;
            int take = R - pre;
            take = take < 0 ? 0 : (take > cnt ? cnt : take);
            while (take-- > 0) {
                const int bit = __ffs(w) - 1;
                w &= w - 1;
                const unsigned slot = atomicAdd(&slotS[row], 1u);
                if (slot < KNB) outbase[(size_t)row * KNB + slot] = cloud * PPTS + lane * 32 + bit;
            }
        }
    }
    __syncthreads();
    // safety fill (provably slot==KNB; keep guard)
    if (tid < RPB) {
        for (unsigned s = slotS[tid]; s < KNB; ++s)
            outbase[(size_t)tid * KNB + s] = cloud * PPTS + pl0 + tid;
    }
}

// ---------------------------------------------------------------------------
// Edge GEMM: A = x @ (W_top - W_bot) + b ; Bm = x @ W_bot
// ---------------------------------------------------------------------------
template<int F, int FO>
__global__ __launch_bounds__(256) void edge_gemm_kernel(const float* __restrict__ x,
                                                        const float* __restrict__ W,
                                                        const float* __restrict__ bias,
                                                        float* __restrict__ A,
                                                        float* __restrict__ Bm) {
    constexpr int RT  = 16;
    constexpr int RS  = 256 / FO;
    constexpr int RPT = RT / RS;
    __shared__ float xs[RT][F];
    const int tid = threadIdx.x;
    const int n0  = blockIdx.x * RT;
    for (int i = tid; i < RT * F; i += 256)
        xs[i / F][i % F] = x[(size_t)n0 * F + i];
    __syncthreads();

    const int o  = tid % FO;
    const int r0 = tid / FO;
    float accA[RPT], accB[RPT];
#pragma unroll
    for (int i = 0; i < RPT; ++i) { accA[i] = 0.f; accB[i] = 0.f; }

    for (int f = 0; f < F; ++f) {
        const float wt = W[(size_t)f * FO + o];
        const float wb = W[(size_t)(F + f) * FO + o];
        const float wd = wt - wb;
#pragma unroll
        for (int i = 0; i < RPT; ++i) {
            const float xv = xs[r0 + i * RS][f];
            accA[i] = fmaf(xv, wd, accA[i]);
            accB[i] = fmaf(xv, wb, accB[i]);
        }
    }
    const float bo = bias[o];
#pragma unroll
    for (int i = 0; i < RPT; ++i) {
        const size_t row = (size_t)(n0 + r0 + i * RS);
        A[row * FO + o]  = accA[i] + bo;
        Bm[row * FO + o] = accB[i];
    }
}

// ---------------------------------------------------------------------------
// Combine: x_out[n,o] = relu(A[n,o] + max_k Bm[nbr[n,k],o])
// ---------------------------------------------------------------------------
template<int FO>
__global__ __launch_bounds__(256) void combine_kernel(const float* __restrict__ A,
                                                      const float* __restrict__ Bm,
                                                      const int* __restrict__ nbr,
                                                      float* __restrict__ xout) {
    const int idx = blockIdx.x * 256 + threadIdx.x;
    const int n = idx / FO;
    const int o = idx % FO;
    const int* nb = nbr + (size_t)n * KNB;
    float m = -FLT_MAX;
#pragma unroll 8
    for (int k = 0; k < KNB; ++k)
        m = fmaxf(m, Bm[(size_t)nb[k] * FO + o]);
    const float v = A[idx] + m;
    xout[idx] = v > 0.f ? v : 0.f;
}

// ---------------------------------------------------------------------------
// Classifier + loss
// ---------------------------------------------------------------------------
__global__ __launch_bounds__(256) void classifier_kernel(const float* __restrict__ x,
                                                         const float* __restrict__ Wc,
                                                         const float* __restrict__ bc,
                                                         const int* __restrict__ target,
                                                         float* __restrict__ probs,
                                                         float* __restrict__ lossbuf) {
    const int tid = threadIdx.x;
    const int lane = tid & 63;
    const int n = blockIdx.x * 4 + (tid >> 6);
    const float* xr = x + (size_t)n * 256;
    float logit = -FLT_MAX;
    if (lane < NCLS) {
        float acc = bc[lane];
        for (int f = 0; f < 256; ++f)
            acc = fmaf(xr[f], Wc[f * NCLS + lane], acc);
        logit = acc;
    }
    float m = logit;
#pragma unroll
    for (int off = 32; off; off >>= 1) m = fmaxf(m, __shfl_xor(m, off));
    const float e = (lane < NCLS) ? __expf(logit - m) : 0.f;
    float s = e;
#pragma unroll
    for (int off = 32; off; off >>= 1) s += __shfl_xor(s, off);
    if (lane < NCLS) probs[(size_t)n * NCLS + lane] = e / s;
    const float lt = __shfl(logit, target[n]);
    if (lane == 0) lossbuf[n] = logf(s) - (lt - m);
}

__global__ __launch_bounds__(256) void loss_reduce_kernel(const float* __restrict__ lossbuf,
                                                          float* __restrict__ out) {
    __shared__ float s[256];
    float acc = 0.f;
    for (int i = threadIdx.x; i < NPTS; i += 256) acc += lossbuf[i];
    s[threadIdx.x] = acc;
    __syncthreads();
    for (int off = 128; off; off >>= 1) {
        if (threadIdx.x < off) s[threadIdx.x] += s[threadIdx.x + off];
        __syncthreads();
    }
    if (threadIdx.x == 0) out[0] = s[0] / (float)NPTS;
}

extern "C" void kernel_launch(void* const* d_in, const int* in_sizes, int n_in,
                              void* d_out, int out_size, void* d_ws, size_t ws_size,
                              hipStream_t stream) {
    (void)in_sizes; (void)n_in; (void)out_size; (void)ws_size;
    const float* x_in   = (const float*)d_in[0];
    const int*   target = (const int*)d_in[2];
    const float* W1 = (const float*)d_in[3];
    const float* b1 = (const float*)d_in[4];
    const float* W2 = (const float*)d_in[5];
    const float* b2 = (const float*)d_in[6];
    const float* W3 = (const float*)d_in[7];
    const float* b3 = (const float*)d_in[8];
    const float* Wc = (const float*)d_in[9];
    const float* bc = (const float*)d_in[10];

    char* ws = (char*)d_ws;
    float* X       = (float*)(ws);                                // N*256 f32
    float* A       = (float*)(ws + (size_t)16 * 1024 * 1024);
    float* Bm      = (float*)(ws + (size_t)32 * 1024 * 1024);
    int*   nbr     = (int*)  (ws + (size_t)48 * 1024 * 1024);
    float* lossbuf = (float*)(ws + (size_t)50 * 1024 * 1024);

    float* outF  = (float*)d_out;
    float* probs = outF + 1;

    // ---- layer 1 (3 -> 64) ----
    knn_kernel<3><<<NPTS / RPB, 512, 0, stream>>>(x_in, nbr);
    edge_gemm_kernel<3, 64><<<NPTS / 16, 256, 0, stream>>>(x_in, W1, b1, A, Bm);
    combine_kernel<64><<<NPTS * 64 / 256, 256, 0, stream>>>(A, Bm, nbr, X);

    // ---- layer 2 (64 -> 128) ----
    knn_kernel<64><<<NPTS / RPB, 512, 0, stream>>>(X, nbr);
    edge_gemm_kernel<64, 128><<<NPTS / 16, 256, 0, stream>>>(X, W2, b2, A, Bm);
    combine_kernel<128><<<NPTS * 128 / 256, 256, 0, stream>>>(A, Bm, nbr, X);

    // ---- layer 3 (128 -> 256) ----
    knn_kernel<128><<<NPTS / RPB, 512, 0, stream>>>(X, nbr);
    edge_gemm_kernel<128, 256><<<NPTS / 16, 256, 0, stream>>>(X, W3, b3, A, Bm);
    combine_kernel<256><<<NPTS * 256 / 256, 256, 0, stream>>>(A, Bm, nbr, X);

    // ---- classifier + loss ----
    classifier_kernel<<<NPTS / 4, 256, 0, stream>>>(X, Wc, bc, target, probs, lossbuf);
    loss_reduce_kernel<<<1, 256, 0, stream>>>(lossbuf, outF);
}

// Round 9
// 690.687 us; speedup vs baseline: 1.4101x; 1.4101x over previous
//
#include <hip/hip_runtime.h>
#include <float.h>
#include <math.h>

#define BCLOUDS 16
#define PPTS    1024
#define NPTS    (BCLOUDS * PPTS)
#define KNB     32
#define NCLS    40
#define RPB     8                  // rows per dist block
#define CCH     4                  // clouds per chunk
#define NBIN    256
#define HPADW   (NBIN + NBIN / 16)
#define SELFM   0xFFFFFFFFu        // self marker: above every real distance bit pattern

__device__ __forceinline__ int hidx(int b) { return b + (b >> 4); }

// ---------------------------------------------------------------------------
// Transpose + norms: xT[cloud][f][p] = x[cloud*1024+p][f]; qn[p] = |x_p|^2
// ---------------------------------------------------------------------------
template<int F>
__global__ __launch_bounds__(256) void xpose_kernel(const float* __restrict__ x,
                                                    float* __restrict__ xT,
                                                    float* __restrict__ qn) {
    const int p = blockIdx.x * 256 + threadIdx.x;   // global point id
    const int cloud = p >> 10, pl = p & 1023;
    const float* xr = x + (size_t)p * F;
    float* xTc = xT + (size_t)cloud * F * PPTS;
    float s = 0.f;
    for (int f = 0; f < F; ++f) {
        const float v = xr[f];
        s = fmaf(v, v, s);
        xTc[(size_t)f * PPTS + pl] = v;             // coalesced along pl
    }
    qn[p] = s;
}

// ---------------------------------------------------------------------------
// Distance matrix for one 4-cloud chunk: D[rowrel][q] = bits(d2) (SELFM on diag)
// 8 rows/block, 512 threads, candidate features read COALESCED from xT.
// ---------------------------------------------------------------------------
template<int F>
__global__ __launch_bounds__(512, 4) void dist_kernel(const float* __restrict__ x,
                                                      const float* __restrict__ xT,
                                                      const float* __restrict__ qn,
                                                      int c0,
                                                      unsigned* __restrict__ D) {
    __shared__ float xp[RPB][F];
    __shared__ float rn[RPB];
    const int tid = threadIdx.x;
    const int cloudrel = blockIdx.x >> 7;           // 128 blocks per cloud
    const int pl0 = (blockIdx.x & 127) * RPB;
    const int cloud = c0 + cloudrel;

    const size_t xbase = (size_t)(cloud * PPTS + pl0) * F;
    for (int i = tid; i < RPB * F; i += 512)
        xp[i / F][i % F] = x[xbase + i];
    if (tid < RPB) rn[tid] = qn[cloud * PPTS + pl0 + tid];
    __syncthreads();

    const float* xTc = xT + (size_t)cloud * F * PPTS;
    const float qv0 = qn[cloud * PPTS + tid];
    const float qv1 = qn[cloud * PPTS + tid + 512];

    float acc[RPB][2];
#pragma unroll
    for (int r = 0; r < RPB; ++r) { acc[r][0] = 0.f; acc[r][1] = 0.f; }

#pragma unroll 4
    for (int f = 0; f < F; ++f) {
        const float v0 = xTc[(size_t)f * PPTS + tid];
        const float v1 = xTc[(size_t)f * PPTS + tid + 512];
#pragma unroll
        for (int r = 0; r < RPB; ++r) {
            const float xv = xp[r][f];
            acc[r][0] = fmaf(v0, xv, acc[r][0]);
            acc[r][1] = fmaf(v1, xv, acc[r][1]);
        }
    }
#pragma unroll
    for (int c = 0; c < 2; ++c) {
        const int q = tid + c * 512;
        const float qv = c ? qv1 : qv0;
#pragma unroll
        for (int r = 0; r < RPB; ++r) {
            float d2 = rn[r] + qv - 2.f * acc[r][c];
            d2 = fmaxf(d2, 0.f);
            const int rowrel = (cloudrel << 10) + pl0 + r;
            D[(size_t)rowrel * PPTS + q] = (q == pl0 + r) ? SELFM : __float_as_uint(d2);
        }
    }
}

// ---------------------------------------------------------------------------
// Selection (R6-proven logic, verbatim): one wave per row, reading D rows
// coalesced. prefilter -> <=2 hist passes -> value-group extraction.
// ---------------------------------------------------------------------------
__global__ __launch_bounds__(256) void select_kernel(const unsigned* __restrict__ D,
                                                     int c0,
                                                     int* __restrict__ nbr) {
    __shared__ unsigned hist[4][HPADW];
    const int tid = threadIdx.x;
    const int lane = tid & 63;
    const int wave = tid >> 6;
    const int rowrel = blockIdx.x * 4 + wave;       // 0..4095
    const int cloud = c0 + (rowrel >> 10);
    const int p = rowrel & 1023;
    const unsigned* Drow = D + (size_t)rowrel * PPTS;
    unsigned* hw = hist[wave];

    unsigned bits[16];
#pragma unroll
    for (int i = 0; i < 16; ++i) bits[i] = Drow[lane + i * 64];

    // reduce: gmin over all, T = max of lower-32 per-lane minima
    unsigned m = bits[0];
#pragma unroll
    for (int i = 1; i < 16; ++i) m = min(m, bits[i]);
    unsigned gmin = m;
    unsigned tmax = (lane < 32) ? m : 0u;
#pragma unroll
    for (int off = 1; off < 64; off <<= 1) {
        gmin = min(gmin, (unsigned)__shfl_xor((int)gmin, off));
        tmax = max(tmax, (unsigned)__shfl_xor((int)tmax, off));
    }

    unsigned sm = 0u, nam = 0xFFFFu;
    int R = KNB;
    unsigned base = gmin;
    int shift = 0;
    bool do_hist = tmax > gmin;
    if (do_hist) {
        const unsigned span = tmax - gmin;
        const int lg = 31 - __clz(span);
        shift = lg > 7 ? lg - 7 : 0;
    }

#pragma unroll 1
    for (int pass = 0; pass < 2 && do_hist; ++pass) {
        int bin[16];
#pragma unroll
        for (int j = 0; j < 5; ++j) { const int k2 = lane + j * 64; if (k2 < HPADW) hw[k2] = 0u; }
#pragma unroll
        for (int i = 0; i < 16; ++i) {
            if ((nam >> i) & 1) {
                const unsigned d = bits[i] - base;
                int b = (int)(d >> shift);
                b = b > 255 ? 255 : b;                // junk/self clamp to 255
                bin[i] = b;
                atomicAdd(&hw[hidx(b)], 1u);
            } else bin[i] = 256;
        }
        unsigned h[4];
        int cnt = 0;
#pragma unroll
        for (int j = 0; j < 4; ++j) { h[j] = hw[hidx(lane * 4 + j)]; cnt += (int)h[j]; }
        int inc = cnt;
#pragma unroll
        for (int off = 1; off < 64; off <<= 1) {
            const int nv = __shfl_up(inc, off);
            if (lane >= off) inc += nv;
        }
        const int pre = inc - cnt;
        const bool found = (pre < R && R <= inc);
        unsigned pk = 0;
        if (found) {
            int c = pre, bb = -1, cb = 0; unsigned hbv = 0;
#pragma unroll
            for (int j = 0; j < 4; ++j) {
                if (bb < 0) {
                    if (c + (int)h[j] >= R) { bb = lane * 4 + j; hbv = h[j]; cb = c; }
                    else c += (int)h[j];
                }
            }
            pk = (unsigned)bb | ((unsigned)cb << 8) | (hbv << 16);
        }
        const unsigned long long fm = __ballot(found);
        pk = (unsigned)__shfl((int)pk, __ffsll(fm) - 1);
        const int bbin = (int)(pk & 255u);
        const int cb   = (int)((pk >> 8) & 255u);
        const int hb   = (int)(pk >> 16);
        const int need = R - cb;
        unsigned nnam = 0u;
#pragma unroll
        for (int i = 0; i < 16; ++i) {
            if (bin[i] < bbin) sm |= 1u << i;
            else if (bin[i] == bbin) nnam |= 1u << i;
        }
        if (hb == need && bbin != 255) {
            sm |= nnam; R = 0; do_hist = false;
        } else {
            nam = nnam; R = need;
            if (R <= 4 || shift == 0) do_hist = false;
            else {
                base += (unsigned)bbin << shift;
                shift = shift > 8 ? shift - 8 : 0;
            }
        }
    }

    // value-group extraction: invariant popcount(nam over wave) >= R
#pragma unroll 1
    while (R > 0) {
        unsigned lmin = 0xFFFFFFFFu;
#pragma unroll
        for (int i = 0; i < 16; ++i)
            if ((nam >> i) & 1) lmin = min(lmin, bits[i]);
        unsigned vmin = lmin;
#pragma unroll
        for (int off = 1; off < 64; off <<= 1)
            vmin = min(vmin, (unsigned)__shfl_xor((int)vmin, off));
        unsigned eq = 0u;
#pragma unroll
        for (int i = 0; i < 16; ++i)
            if (((nam >> i) & 1) && bits[i] == vmin) eq |= 1u << i;
        int tot = __popc(eq);
#pragma unroll
        for (int off = 1; off < 64; off <<= 1) tot += __shfl_xor(tot, off);
        if (tot <= R) {
            sm |= eq; nam &= ~eq; R -= tot;
        } else {
#pragma unroll
            for (int i = 0; i < 16; ++i) {
                if (R > 0) {
                    const bool c2 = (eq >> i) & 1;
                    const unsigned long long mb = __ballot(c2);
                    const int t2 = (int)__popcll(mb);
                    if (t2 <= R) { if (c2) sm |= 1u << i; R -= t2; }
                    else {
                        const unsigned long long lower = mb & ((1ull << lane) - 1ull);
                        if (c2 && (int)__popcll(lower) < R) sm |= 1u << i;
                        R = 0;
                    }
                }
            }
        }
    }

    // emit: ballot-prefix compaction
    int* out = nbr + (size_t)(cloud * PPTS + p) * KNB;
    int tot = 0;
#pragma unroll
    for (int i = 0; i < 16; ++i) {
        const bool c2 = (sm >> i) & 1;
        const unsigned long long mb = __ballot(c2);
        if (c2) {
            const int slot = tot + (int)__popcll(mb & ((1ull << lane) - 1ull));
            if (slot < KNB) out[slot] = cloud * PPTS + lane + i * 64;
        }
        tot += (int)__popcll(mb);
    }
    if (lane == 0)
        for (int s = tot; s < KNB; ++s) out[s] = cloud * PPTS + p;
}

// ---------------------------------------------------------------------------
// Edge GEMM: A = x @ (W_top - W_bot) + b ; Bm = x @ W_bot
// ---------------------------------------------------------------------------
template<int F, int FO>
__global__ __launch_bounds__(256) void edge_gemm_kernel(const float* __restrict__ x,
                                                        const float* __restrict__ W,
                                                        const float* __restrict__ bias,
                                                        float* __restrict__ A,
                                                        float* __restrict__ Bm) {
    constexpr int RT  = 16;
    constexpr int RS  = 256 / FO;
    constexpr int RPT = RT / RS;
    __shared__ float xs[RT][F];
    const int tid = threadIdx.x;
    const int n0  = blockIdx.x * RT;
    for (int i = tid; i < RT * F; i += 256)
        xs[i / F][i % F] = x[(size_t)n0 * F + i];
    __syncthreads();

    const int o  = tid % FO;
    const int r0 = tid / FO;
    float accA[RPT], accB[RPT];
#pragma unroll
    for (int i = 0; i < RPT; ++i) { accA[i] = 0.f; accB[i] = 0.f; }

    for (int f = 0; f < F; ++f) {
        const float wt = W[(size_t)f * FO + o];
        const float wb = W[(size_t)(F + f) * FO + o];
        const float wd = wt - wb;
#pragma unroll
        for (int i = 0; i < RPT; ++i) {
            const float xv = xs[r0 + i * RS][f];
            accA[i] = fmaf(xv, wd, accA[i]);
            accB[i] = fmaf(xv, wb, accB[i]);
        }
    }
    const float bo = bias[o];
#pragma unroll
    for (int i = 0; i < RPT; ++i) {
        const size_t row = (size_t)(n0 + r0 + i * RS);
        A[row * FO + o]  = accA[i] + bo;
        Bm[row * FO + o] = accB[i];
    }
}

// ---------------------------------------------------------------------------
// Combine: x_out[n,o] = relu(A[n,o] + max_k Bm[nbr[n,k],o])
// ---------------------------------------------------------------------------
template<int FO>
__global__ __launch_bounds__(256) void combine_kernel(const float* __restrict__ A,
                                                      const float* __restrict__ Bm,
                                                      const int* __restrict__ nbr,
                                                      float* __restrict__ xout) {
    const int idx = blockIdx.x * 256 + threadIdx.x;
    const int n = idx / FO;
    const int o = idx % FO;
    const int* nb = nbr + (size_t)n * KNB;
    float m = -FLT_MAX;
#pragma unroll 8
    for (int k = 0; k < KNB; ++k)
        m = fmaxf(m, Bm[(size_t)nb[k] * FO + o]);
    const float v = A[idx] + m;
    xout[idx] = v > 0.f ? v : 0.f;
}

// ---------------------------------------------------------------------------
// Classifier + loss
// ---------------------------------------------------------------------------
__global__ __launch_bounds__(256) void classifier_kernel(const float* __restrict__ x,
                                                         const float* __restrict__ Wc,
                                                         const float* __restrict__ bc,
                                                         const int* __restrict__ target,
                                                         float* __restrict__ probs,
                                                         float* __restrict__ lossbuf) {
    const int tid = threadIdx.x;
    const int lane = tid & 63;
    const int n = blockIdx.x * 4 + (tid >> 6);
    const float* xr = x + (size_t)n * 256;
    float logit = -FLT_MAX;
    if (lane < NCLS) {
        float acc = bc[lane];
        for (int f = 0; f < 256; ++f)
            acc = fmaf(xr[f], Wc[f * NCLS + lane], acc);
        logit = acc;
    }
    float m = logit;
#pragma unroll
    for (int off = 32; off; off >>= 1) m = fmaxf(m, __shfl_xor(m, off));
    const float e = (lane < NCLS) ? __expf(logit - m) : 0.f;
    float s = e;
#pragma unroll
    for (int off = 32; off; off >>= 1) s += __shfl_xor(s, off);
    if (lane < NCLS) probs[(size_t)n * NCLS + lane] = e / s;
    const float lt = __shfl(logit, target[n]);
    if (lane == 0) lossbuf[n] = logf(s) - (lt - m);
}

__global__ __launch_bounds__(256) void loss_reduce_kernel(const float* __restrict__ lossbuf,
                                                          float* __restrict__ out) {
    __shared__ float s[256];
    float acc = 0.f;
    for (int i = threadIdx.x; i < NPTS; i += 256) acc += lossbuf[i];
    s[threadIdx.x] = acc;
    __syncthreads();
    for (int off = 128; off; off >>= 1) {
        if (threadIdx.x < off) s[threadIdx.x] += s[threadIdx.x + off];
        __syncthreads();
    }
    if (threadIdx.x == 0) out[0] = s[0] / (float)NPTS;
}

extern "C" void kernel_launch(void* const* d_in, const int* in_sizes, int n_in,
                              void* d_out, int out_size, void* d_ws, size_t ws_size,
                              hipStream_t stream) {
    (void)in_sizes; (void)n_in; (void)out_size; (void)ws_size;
    const float* x_in   = (const float*)d_in[0];
    const int*   target = (const int*)d_in[2];
    const float* W1 = (const float*)d_in[3];
    const float* b1 = (const float*)d_in[4];
    const float* W2 = (const float*)d_in[5];
    const float* b2 = (const float*)d_in[6];
    const float* W3 = (const float*)d_in[7];
    const float* b3 = (const float*)d_in[8];
    const float* Wc = (const float*)d_in[9];
    const float* bc = (const float*)d_in[10];

    // all buffers inside the proven-safe first 50MB+64KB of ws
    char* ws = (char*)d_ws;
    float*    X       = (float*)(ws);                               // [0,16M)
    unsigned* Dm      = (unsigned*)(ws + (size_t)16 * 1024 * 1024); // [16,32M) chunk D (aliases A later)
    float*    xT      = (float*)(ws + (size_t)32 * 1024 * 1024);    // [32,40M) (aliases Bm later)
    float*    qn      = (float*)(ws + (size_t)40 * 1024 * 1024);    // 64KB     (aliases Bm later)
    float*    A       = (float*)(ws + (size_t)16 * 1024 * 1024);
    float*    Bm      = (float*)(ws + (size_t)32 * 1024 * 1024);
    int*      nbr     = (int*)  (ws + (size_t)48 * 1024 * 1024);    // [48,50M)
    float*    lossbuf = (float*)(ws + (size_t)50 * 1024 * 1024);    // 64KB

    float* outF  = (float*)d_out;
    float* probs = outF + 1;

    // ---- layer 1 (3 -> 64) ----
    xpose_kernel<3><<<NPTS / 256, 256, 0, stream>>>(x_in, xT, qn);
    for (int c0 = 0; c0 < BCLOUDS; c0 += CCH) {
        dist_kernel<3><<<CCH * PPTS / RPB, 512, 0, stream>>>(x_in, xT, qn, c0, Dm);
        select_kernel<<<CCH * PPTS / 4, 256, 0, stream>>>(Dm, c0, nbr);
    }
    edge_gemm_kernel<3, 64><<<NPTS / 16, 256, 0, stream>>>(x_in, W1, b1, A, Bm);
    combine_kernel<64><<<NPTS * 64 / 256, 256, 0, stream>>>(A, Bm, nbr, X);

    // ---- layer 2 (64 -> 128) ----
    xpose_kernel<64><<<NPTS / 256, 256, 0, stream>>>(X, xT, qn);
    for (int c0 = 0; c0 < BCLOUDS; c0 += CCH) {
        dist_kernel<64><<<CCH * PPTS / RPB, 512, 0, stream>>>(X, xT, qn, c0, Dm);
        select_kernel<<<CCH * PPTS / 4, 256, 0, stream>>>(Dm, c0, nbr);
    }
    edge_gemm_kernel<64, 128><<<NPTS / 16, 256, 0, stream>>>(X, W2, b2, A, Bm);
    combine_kernel<128><<<NPTS * 128 / 256, 256, 0, stream>>>(A, Bm, nbr, X);

    // ---- layer 3 (128 -> 256) ----
    xpose_kernel<128><<<NPTS / 256, 256, 0, stream>>>(X, xT, qn);
    for (int c0 = 0; c0 < BCLOUDS; c0 += CCH) {
        dist_kernel<128><<<CCH * PPTS / RPB, 512, 0, stream>>>(X, xT, qn, c0, Dm);
        select_kernel<<<CCH * PPTS / 4, 256, 0, stream>>>(Dm, c0, nbr);
    }
    edge_gemm_kernel<128, 256><<<NPTS / 16, 256, 0, stream>>>(X, W3, b3, A, Bm);
    combine_kernel<256><<<NPTS * 256 / 256, 256, 0, stream>>>(A, Bm, nbr, X);

    // ---- classifier + loss ----
    classifier_kernel<<<NPTS / 4, 256, 0, stream>>>(X, Wc, bc, target, probs, lossbuf);
    loss_reduce_kernel<<<1, 256, 0, stream>>>(lossbuf, outF);
}

// Round 10
// 587.576 us; speedup vs baseline: 1.6575x; 1.1755x over previous
//
#include <hip/hip_runtime.h>
#include <float.h>
#include <math.h>

#define BCLOUDS 16
#define PPTS    1024
#define NPTS    (BCLOUDS * PPTS)
#define KNB     32
#define NCLS    40
#define RPB     8                  // rows per dist block
#define CCH     8                  // clouds per chunk (D chunk = 32 MB)
#define NBIN    256
#define HPADW   (NBIN + NBIN / 16)
#define SELFM   0xFFFFFFFFu        // self marker: above every real distance bit pattern

__device__ __forceinline__ int hidx(int b) { return b + (b >> 4); }

// ---------------------------------------------------------------------------
// Distance matrix for one CCH-cloud chunk: D[rowrel][q] = bits(d2), SELFM diag.
// R4-proven distance phase: 8 query rows in LDS, candidate rows streamed as
// float4 (cloud slice is L2-resident), candidate self-dot fused in-register.
// ---------------------------------------------------------------------------
template<int F>
__global__ __launch_bounds__(512, 4) void dist_kernel(const float* __restrict__ x,
                                                      int c0,
                                                      unsigned* __restrict__ D) {
    __shared__ float xp[RPB][F];
    __shared__ float rn[RPB];
    const int tid = threadIdx.x;
    const int cloudrel = blockIdx.x >> 7;           // 128 blocks per cloud
    const int pl0 = (blockIdx.x & 127) * RPB;
    const int cloud = c0 + cloudrel;
    const float* xc = x + (size_t)cloud * PPTS * F;

    for (int i = tid; i < RPB * F; i += 512)
        xp[i / F][i % F] = xc[(size_t)(pl0 + i / F) * F + (i % F)];
    __syncthreads();
    if (tid < RPB) {
        float s = 0.f;
        for (int f = 0; f < F; ++f) { const float v = xp[tid][f]; s = fmaf(v, v, s); }
        rn[tid] = s;
    }
    __syncthreads();

    float acc[RPB][2];
    float qnv[2];
#pragma unroll
    for (int c = 0; c < 2; ++c) qnv[c] = 0.f;
#pragma unroll
    for (int r = 0; r < RPB; ++r)
#pragma unroll
        for (int c = 0; c < 2; ++c) acc[r][c] = 0.f;

    if constexpr (F % 4 == 0) {
        const float4* xc4 = reinterpret_cast<const float4*>(xc);
#pragma unroll 2
        for (int f4 = 0; f4 < F / 4; ++f4) {
            float4 vq[2];
#pragma unroll
            for (int c = 0; c < 2; ++c) vq[c] = xc4[(size_t)(tid + c * 512) * (F / 4) + f4];
#pragma unroll
            for (int c = 0; c < 2; ++c) {
                qnv[c] = fmaf(vq[c].x, vq[c].x, qnv[c]);
                qnv[c] = fmaf(vq[c].y, vq[c].y, qnv[c]);
                qnv[c] = fmaf(vq[c].z, vq[c].z, qnv[c]);
                qnv[c] = fmaf(vq[c].w, vq[c].w, qnv[c]);
            }
            float4 xr[RPB];
#pragma unroll
            for (int r = 0; r < RPB; ++r) xr[r] = *reinterpret_cast<const float4*>(&xp[r][f4 * 4]);
#pragma unroll
            for (int r = 0; r < RPB; ++r)
#pragma unroll
                for (int c = 0; c < 2; ++c) {
                    acc[r][c] = fmaf(vq[c].x, xr[r].x, acc[r][c]);
                    acc[r][c] = fmaf(vq[c].y, xr[r].y, acc[r][c]);
                    acc[r][c] = fmaf(vq[c].z, xr[r].z, acc[r][c]);
                    acc[r][c] = fmaf(vq[c].w, xr[r].w, acc[r][c]);
                }
        }
    } else {
        for (int f = 0; f < F; ++f) {
            float vq[2];
#pragma unroll
            for (int c = 0; c < 2; ++c) vq[c] = xc[(size_t)(tid + c * 512) * F + f];
#pragma unroll
            for (int c = 0; c < 2; ++c) qnv[c] = fmaf(vq[c], vq[c], qnv[c]);
#pragma unroll
            for (int r = 0; r < RPB; ++r) {
                const float xv = xp[r][f];
#pragma unroll
                for (int c = 0; c < 2; ++c) acc[r][c] = fmaf(vq[c], xv, acc[r][c]);
            }
        }
    }
#pragma unroll
    for (int c = 0; c < 2; ++c) {
        const int q = tid + c * 512;
#pragma unroll
        for (int r = 0; r < RPB; ++r) {
            float d2 = rn[r] + qnv[c] - 2.f * acc[r][c];
            d2 = fmaxf(d2, 0.f);
            const int rowrel = (cloudrel << 10) + pl0 + r;
            D[(size_t)rowrel * PPTS + q] = (q == pl0 + r) ? SELFM : __float_as_uint(d2);
        }
    }
}

// ---------------------------------------------------------------------------
// Selection (R6-proven logic, verbatim): one wave per row, D rows coalesced.
// prefilter -> <=2 hist passes -> value-group extraction. Exact tie-break.
// ---------------------------------------------------------------------------
__global__ __launch_bounds__(256) void select_kernel(const unsigned* __restrict__ D,
                                                     int c0,
                                                     int* __restrict__ nbr) {
    __shared__ unsigned hist[4][HPADW];
    const int tid = threadIdx.x;
    const int lane = tid & 63;
    const int wave = tid >> 6;
    const int rowrel = blockIdx.x * 4 + wave;
    const int cloud = c0 + (rowrel >> 10);
    const int p = rowrel & 1023;
    const unsigned* Drow = D + (size_t)rowrel * PPTS;
    unsigned* hw = hist[wave];

    unsigned bits[16];
#pragma unroll
    for (int i = 0; i < 16; ++i) bits[i] = Drow[lane + i * 64];

    unsigned m = bits[0];
#pragma unroll
    for (int i = 1; i < 16; ++i) m = min(m, bits[i]);
    unsigned gmin = m;
    unsigned tmax = (lane < 32) ? m : 0u;
#pragma unroll
    for (int off = 1; off < 64; off <<= 1) {
        gmin = min(gmin, (unsigned)__shfl_xor((int)gmin, off));
        tmax = max(tmax, (unsigned)__shfl_xor((int)tmax, off));
    }

    unsigned sm = 0u, nam = 0xFFFFu;
    int R = KNB;
    unsigned base = gmin;
    int shift = 0;
    bool do_hist = tmax > gmin;
    if (do_hist) {
        const unsigned span = tmax - gmin;
        const int lg = 31 - __clz(span);
        shift = lg > 7 ? lg - 7 : 0;
    }

#pragma unroll 1
    for (int pass = 0; pass < 2 && do_hist; ++pass) {
        int bin[16];
#pragma unroll
        for (int j = 0; j < 5; ++j) { const int k2 = lane + j * 64; if (k2 < HPADW) hw[k2] = 0u; }
#pragma unroll
        for (int i = 0; i < 16; ++i) {
            if ((nam >> i) & 1) {
                const unsigned d = bits[i] - base;
                int b = (int)(d >> shift);
                b = b > 255 ? 255 : b;
                bin[i] = b;
                atomicAdd(&hw[hidx(b)], 1u);
            } else bin[i] = 256;
        }
        unsigned h[4];
        int cnt = 0;
#pragma unroll
        for (int j = 0; j < 4; ++j) { h[j] = hw[hidx(lane * 4 + j)]; cnt += (int)h[j]; }
        int inc = cnt;
#pragma unroll
        for (int off = 1; off < 64; off <<= 1) {
            const int nv = __shfl_up(inc, off);
            if (lane >= off) inc += nv;
        }
        const int pre = inc - cnt;
        const bool found = (pre < R && R <= inc);
        unsigned pk = 0;
        if (found) {
            int c = pre, bb = -1, cb = 0; unsigned hbv = 0;
#pragma unroll
            for (int j = 0; j < 4; ++j) {
                if (bb < 0) {
                    if (c + (int)h[j] >= R) { bb = lane * 4 + j; hbv = h[j]; cb = c; }
                    else c += (int)h[j];
                }
            }
            pk = (unsigned)bb | ((unsigned)cb << 8) | (hbv << 16);
        }
        const unsigned long long fm = __ballot(found);
        pk = (unsigned)__shfl((int)pk, __ffsll(fm) - 1);
        const int bbin = (int)(pk & 255u);
        const int cb   = (int)((pk >> 8) & 255u);
        const int hb   = (int)(pk >> 16);
        const int need = R - cb;
        unsigned nnam = 0u;
#pragma unroll
        for (int i = 0; i < 16; ++i) {
            if (bin[i] < bbin) sm |= 1u << i;
            else if (bin[i] == bbin) nnam |= 1u << i;
        }
        if (hb == need && bbin != 255) {
            sm |= nnam; R = 0; do_hist = false;
        } else {
            nam = nnam; R = need;
            if (R <= 4 || shift == 0) do_hist = false;
            else {
                base += (unsigned)bbin << shift;
                shift = shift > 8 ? shift - 8 : 0;
            }
        }
    }

#pragma unroll 1
    while (R > 0) {
        unsigned lmin = 0xFFFFFFFFu;
#pragma unroll
        for (int i = 0; i < 16; ++i)
            if ((nam >> i) & 1) lmin = min(lmin, bits[i]);
        unsigned vmin = lmin;
#pragma unroll
        for (int off = 1; off < 64; off <<= 1)
            vmin = min(vmin, (unsigned)__shfl_xor((int)vmin, off));
        unsigned eq = 0u;
#pragma unroll
        for (int i = 0; i < 16; ++i)
            if (((nam >> i) & 1) && bits[i] == vmin) eq |= 1u << i;
        int tot = __popc(eq);
#pragma unroll
        for (int off = 1; off < 64; off <<= 1) tot += __shfl_xor(tot, off);
        if (tot <= R) {
            sm |= eq; nam &= ~eq; R -= tot;
        } else {
#pragma unroll
            for (int i = 0; i < 16; ++i) {
                if (R > 0) {
                    const bool c2 = (eq >> i) & 1;
                    const unsigned long long mb = __ballot(c2);
                    const int t2 = (int)__popcll(mb);
                    if (t2 <= R) { if (c2) sm |= 1u << i; R -= t2; }
                    else {
                        const unsigned long long lower = mb & ((1ull << lane) - 1ull);
                        if (c2 && (int)__popcll(lower) < R) sm |= 1u << i;
                        R = 0;
                    }
                }
            }
        }
    }

    int* out = nbr + (size_t)(cloud * PPTS + p) * KNB;
    int tot = 0;
#pragma unroll
    for (int i = 0; i < 16; ++i) {
        const bool c2 = (sm >> i) & 1;
        const unsigned long long mb = __ballot(c2);
        if (c2) {
            const int slot = tot + (int)__popcll(mb & ((1ull << lane) - 1ull));
            if (slot < KNB) out[slot] = cloud * PPTS + lane + i * 64;
        }
        tot += (int)__popcll(mb);
    }
    if (lane == 0)
        for (int s = tot; s < KNB; ++s) out[s] = cloud * PPTS + p;
}

// ---------------------------------------------------------------------------
// Edge GEMM: A = x @ (W_top - W_bot) + b ; Bm = x @ W_bot
// ---------------------------------------------------------------------------
template<int F, int FO>
__global__ __launch_bounds__(256) void edge_gemm_kernel(const float* __restrict__ x,
                                                        const float* __restrict__ W,
                                                        const float* __restrict__ bias,
                                                        float* __restrict__ A,
                                                        float* __restrict__ Bm) {
    constexpr int RT  = 16;
    constexpr int RS  = 256 / FO;
    constexpr int RPT = RT / RS;
    __shared__ float xs[RT][F];
    const int tid = threadIdx.x;
    const int n0  = blockIdx.x * RT;
    for (int i = tid; i < RT * F; i += 256)
        xs[i / F][i % F] = x[(size_t)n0 * F + i];
    __syncthreads();

    const int o  = tid % FO;
    const int r0 = tid / FO;
    float accA[RPT], accB[RPT];
#pragma unroll
    for (int i = 0; i < RPT; ++i) { accA[i] = 0.f; accB[i] = 0.f; }

    for (int f = 0; f < F; ++f) {
        const float wt = W[(size_t)f * FO + o];
        const float wb = W[(size_t)(F + f) * FO + o];
        const float wd = wt - wb;
#pragma unroll
        for (int i = 0; i < RPT; ++i) {
            const float xv = xs[r0 + i * RS][f];
            accA[i] = fmaf(xv, wd, accA[i]);
            accB[i] = fmaf(xv, wb, accB[i]);
        }
    }
    const float bo = bias[o];
#pragma unroll
    for (int i = 0; i < RPT; ++i) {
        const size_t row = (size_t)(n0 + r0 + i * RS);
        A[row * FO + o]  = accA[i] + bo;
        Bm[row * FO + o] = accB[i];
    }
}

// ---------------------------------------------------------------------------
// Combine (float4): x_out[n,o4] = relu(A[n,o4] + max_k Bm[nbr[n,k],o4])
// 4x fewer load instructions than scalar version (1KB per wave-load).
// ---------------------------------------------------------------------------
template<int FO>
__global__ __launch_bounds__(256) void combine_kernel(const float* __restrict__ A,
                                                      const float* __restrict__ Bm,
                                                      const int* __restrict__ nbr,
                                                      float* __restrict__ xout) {
    constexpr int FO4 = FO / 4;
    const int idx = blockIdx.x * 256 + threadIdx.x;   // over N*FO4
    const int n  = idx / FO4;
    const int o4 = idx % FO4;
    const int* nb = nbr + (size_t)n * KNB;
    const float4* B4 = reinterpret_cast<const float4*>(Bm);
    float4 mx = make_float4(-FLT_MAX, -FLT_MAX, -FLT_MAX, -FLT_MAX);
#pragma unroll 8
    for (int k = 0; k < KNB; ++k) {
        const float4 v = B4[(size_t)nb[k] * FO4 + o4];
        mx.x = fmaxf(mx.x, v.x); mx.y = fmaxf(mx.y, v.y);
        mx.z = fmaxf(mx.z, v.z); mx.w = fmaxf(mx.w, v.w);
    }
    const float4 a = reinterpret_cast<const float4*>(A)[idx];
    float4 r;
    r.x = fmaxf(a.x + mx.x, 0.f);
    r.y = fmaxf(a.y + mx.y, 0.f);
    r.z = fmaxf(a.z + mx.z, 0.f);
    r.w = fmaxf(a.w + mx.w, 0.f);
    reinterpret_cast<float4*>(xout)[idx] = r;
}

// ---------------------------------------------------------------------------
// Classifier + loss
// ---------------------------------------------------------------------------
__global__ __launch_bounds__(256) void classifier_kernel(const float* __restrict__ x,
                                                         const float* __restrict__ Wc,
                                                         const float* __restrict__ bc,
                                                         const int* __restrict__ target,
                                                         float* __restrict__ probs,
                                                         float* __restrict__ lossbuf) {
    const int tid = threadIdx.x;
    const int lane = tid & 63;
    const int n = blockIdx.x * 4 + (tid >> 6);
    const float* xr = x + (size_t)n * 256;
    float logit = -FLT_MAX;
    if (lane < NCLS) {
        float acc = bc[lane];
        for (int f = 0; f < 256; ++f)
            acc = fmaf(xr[f], Wc[f * NCLS + lane], acc);
        logit = acc;
    }
    float m = logit;
#pragma unroll
    for (int off = 32; off; off >>= 1) m = fmaxf(m, __shfl_xor(m, off));
    const float e = (lane < NCLS) ? __expf(logit - m) : 0.f;
    float s = e;
#pragma unroll
    for (int off = 32; off; off >>= 1) s += __shfl_xor(s, off);
    if (lane < NCLS) probs[(size_t)n * NCLS + lane] = e / s;
    const float lt = __shfl(logit, target[n]);
    if (lane == 0) lossbuf[n] = logf(s) - (lt - m);
}

__global__ __launch_bounds__(256) void loss_reduce_kernel(const float* __restrict__ lossbuf,
                                                          float* __restrict__ out) {
    __shared__ float s[256];
    float acc = 0.f;
    for (int i = threadIdx.x; i < NPTS; i += 256) acc += lossbuf[i];
    s[threadIdx.x] = acc;
    __syncthreads();
    for (int off = 128; off; off >>= 1) {
        if (threadIdx.x < off) s[threadIdx.x] += s[threadIdx.x + off];
        __syncthreads();
    }
    if (threadIdx.x == 0) out[0] = s[0] / (float)NPTS;
}

extern "C" void kernel_launch(void* const* d_in, const int* in_sizes, int n_in,
                              void* d_out, int out_size, void* d_ws, size_t ws_size,
                              hipStream_t stream) {
    (void)in_sizes; (void)n_in; (void)out_size; (void)ws_size;
    const float* x_in   = (const float*)d_in[0];
    const int*   target = (const int*)d_in[2];
    const float* W1 = (const float*)d_in[3];
    const float* b1 = (const float*)d_in[4];
    const float* W2 = (const float*)d_in[5];
    const float* b2 = (const float*)d_in[6];
    const float* W3 = (const float*)d_in[7];
    const float* b3 = (const float*)d_in[8];
    const float* Wc = (const float*)d_in[9];
    const float* bc = (const float*)d_in[10];

    // proven-safe window [0, 50MB+64KB):
    //   X [0,16M) | D [16M,48M) -> A [16M,32M), Bm [32M,48M) | nbr [48M,50M) | lossbuf [50M,+64K)
    char* ws = (char*)d_ws;
    float*    X       = (float*)(ws);
    unsigned* Dm      = (unsigned*)(ws + (size_t)16 * 1024 * 1024);
    float*    A       = (float*)(ws + (size_t)16 * 1024 * 1024);
    float*    Bm      = (float*)(ws + (size_t)32 * 1024 * 1024);
    int*      nbr     = (int*)  (ws + (size_t)48 * 1024 * 1024);
    float*    lossbuf = (float*)(ws + (size_t)50 * 1024 * 1024);

    float* outF  = (float*)d_out;
    float* probs = outF + 1;

    // ---- layer 1 (3 -> 64) ----
    for (int c0 = 0; c0 < BCLOUDS; c0 += CCH) {
        dist_kernel<3><<<CCH * PPTS / RPB, 512, 0, stream>>>(x_in, c0, Dm);
        select_kernel<<<CCH * PPTS / 4, 256, 0, stream>>>(Dm, c0, nbr);
    }
    edge_gemm_kernel<3, 64><<<NPTS / 16, 256, 0, stream>>>(x_in, W1, b1, A, Bm);
    combine_kernel<64><<<NPTS * 16 / 256, 256, 0, stream>>>(A, Bm, nbr, X);

    // ---- layer 2 (64 -> 128) ----
    for (int c0 = 0; c0 < BCLOUDS; c0 += CCH) {
        dist_kernel<64><<<CCH * PPTS / RPB, 512, 0, stream>>>(X, c0, Dm);
        select_kernel<<<CCH * PPTS / 4, 256, 0, stream>>>(Dm, c0, nbr);
    }
    edge_gemm_kernel<64, 128><<<NPTS / 16, 256, 0, stream>>>(X, W2, b2, A, Bm);
    combine_kernel<128><<<NPTS * 32 / 256, 256, 0, stream>>>(A, Bm, nbr, X);

    // ---- layer 3 (128 -> 256) ----
    for (int c0 = 0; c0 < BCLOUDS; c0 += CCH) {
        dist_kernel<128><<<CCH * PPTS / RPB, 512, 0, stream>>>(X, c0, Dm);
        select_kernel<<<CCH * PPTS / 4, 256, 0, stream>>>(Dm, c0, nbr);
    }
    edge_gemm_kernel<128, 256><<<NPTS / 16, 256, 0, stream>>>(X, W3, b3, A, Bm);
    combine_kernel<256><<<NPTS * 64 / 256, 256, 0, stream>>>(A, Bm, nbr, X);

    // ---- classifier + loss ----
    classifier_kernel<<<NPTS / 4, 256, 0, stream>>>(X, Wc, bc, target, probs, lossbuf);
    loss_reduce_kernel<<<1, 256, 0, stream>>>(lossbuf, outF);
}

// Round 11
// 410.404 us; speedup vs baseline: 2.3731x; 1.4317x over previous
//
#include <hip/hip_runtime.h>
#include <float.h>
#include <math.h>

#define BCLOUDS 16
#define PPTS    1024
#define NPTS    (BCLOUDS * PPTS)
#define KNB     32
#define NCLS    40
#define RPB     8                  // rows per knn block (= waves per block)
#define NBIN    256
#define HPADW   (NBIN + NBIN / 16)
#define SELFM   0xFFFFFFFFu        // self marker: above every real distance bit pattern

__device__ __forceinline__ int hidx(int b) { return b + (b >> 4); }

// ---------------------------------------------------------------------------
// Transpose + norms: xT[cloud][f][p] = x[cloud*1024+p][f]; qn[p] = |x_p|^2
// (R9-proven)
// ---------------------------------------------------------------------------
template<int F>
__global__ __launch_bounds__(256) void xpose_kernel(const float* __restrict__ x,
                                                    float* __restrict__ xT,
                                                    float* __restrict__ qn) {
    const int p = blockIdx.x * 256 + threadIdx.x;   // global point id
    const int cloud = p >> 10, pl = p & 1023;
    const float* xr = x + (size_t)p * F;
    float* xTc = xT + (size_t)cloud * F * PPTS;
    float s = 0.f;
    for (int f = 0; f < F; ++f) {
        const float v = xr[f];
        s = fmaf(v, v, s);
        xTc[(size_t)f * PPTS + pl] = v;             // coalesced along pl
    }
    qn[p] = s;
}

// ---------------------------------------------------------------------------
// Fused kNN: 8 rows/block, 512 threads. Distance phase reads candidates
// COALESCED from xT (R9-proven loop); dmat in LDS (no global D).
// Selection = R6-proven: prefilter -> <=2 hist passes -> group extraction.
// ---------------------------------------------------------------------------
template<int F>
__global__ __launch_bounds__(512, 6) void knn_kernel(const float* __restrict__ x,
                                                     const float* __restrict__ xT,
                                                     const float* __restrict__ qn,
                                                     int* __restrict__ nbr) {
    __shared__ unsigned dmat[RPB][PPTS];
    __shared__ float    xp[RPB][F];
    __shared__ float    rn[RPB];
    __shared__ unsigned hist[RPB][HPADW];

    const int tid   = threadIdx.x;
    const int lane  = tid & 63;
    const int wave  = tid >> 6;            // 0..7
    const int bpc   = PPTS / RPB;          // 128 blocks per cloud
    const int cloud = blockIdx.x / bpc;
    const int pl0   = (blockIdx.x % bpc) * RPB;

    // query rows (row-major read of just 8 rows) + row norms
    const float* xc = x + (size_t)cloud * PPTS * F;
    for (int i = tid; i < RPB * F; i += 512)
        xp[i / F][i % F] = xc[(size_t)(pl0 + i / F) * F + (i % F)];
    __syncthreads();
    if (tid < RPB) {
        float s = 0.f;
        for (int f = 0; f < F; ++f) { const float v = xp[tid][f]; s = fmaf(v, v, s); }
        rn[tid] = s;
    }
    __syncthreads();

    // ---- distances: candidates q = tid, tid+512 read coalesced from xT ----
    const float* xTc = xT + (size_t)cloud * F * PPTS;
    const float qv0 = qn[cloud * PPTS + tid];
    const float qv1 = qn[cloud * PPTS + tid + 512];

    float acc[RPB][2];
#pragma unroll
    for (int r = 0; r < RPB; ++r) { acc[r][0] = 0.f; acc[r][1] = 0.f; }

#pragma unroll 4
    for (int f = 0; f < F; ++f) {
        const float v0 = xTc[(size_t)f * PPTS + tid];
        const float v1 = xTc[(size_t)f * PPTS + tid + 512];
#pragma unroll
        for (int r = 0; r < RPB; ++r) {
            const float xv = xp[r][f];
            acc[r][0] = fmaf(v0, xv, acc[r][0]);
            acc[r][1] = fmaf(v1, xv, acc[r][1]);
        }
    }
#pragma unroll
    for (int c = 0; c < 2; ++c) {
        const int q = tid + c * 512;
        const float qv = c ? qv1 : qv0;
#pragma unroll
        for (int r = 0; r < RPB; ++r) {
            float d2 = rn[r] + qv - 2.f * acc[r][c];
            d2 = fmaxf(d2, 0.f);
            dmat[r][q] = (q == pl0 + r) ? SELFM : __float_as_uint(d2);
        }
    }
    __syncthreads();

    // ---- selection (R6-proven verbatim): wave w handles row w ----
    unsigned* hw = hist[wave];
    const int r = wave;
    unsigned bits[16];
#pragma unroll
    for (int i = 0; i < 16; ++i) bits[i] = dmat[r][lane + i * 64];

    unsigned m = bits[0];
#pragma unroll
    for (int i = 1; i < 16; ++i) m = min(m, bits[i]);
    unsigned gmin = m;
    unsigned tmax = (lane < 32) ? m : 0u;
#pragma unroll
    for (int off = 1; off < 64; off <<= 1) {
        gmin = min(gmin, (unsigned)__shfl_xor((int)gmin, off));
        tmax = max(tmax, (unsigned)__shfl_xor((int)tmax, off));
    }

    unsigned sm = 0u, nam = 0xFFFFu;
    int R = KNB;
    unsigned base = gmin;
    int shift = 0;
    bool do_hist = tmax > gmin;
    if (do_hist) {
        const unsigned span = tmax - gmin;
        const int lg = 31 - __clz(span);
        shift = lg > 7 ? lg - 7 : 0;
    }

#pragma unroll 1
    for (int pass = 0; pass < 2 && do_hist; ++pass) {
        int bin[16];
#pragma unroll
        for (int j = 0; j < 5; ++j) { const int k2 = lane + j * 64; if (k2 < HPADW) hw[k2] = 0u; }
#pragma unroll
        for (int i = 0; i < 16; ++i) {
            if ((nam >> i) & 1) {
                const unsigned d = bits[i] - base;
                int b = (int)(d >> shift);
                b = b > 255 ? 255 : b;                // junk/self clamp to 255
                bin[i] = b;
                atomicAdd(&hw[hidx(b)], 1u);
            } else bin[i] = 256;
        }
        unsigned h[4];
        int cnt = 0;
#pragma unroll
        for (int j = 0; j < 4; ++j) { h[j] = hw[hidx(lane * 4 + j)]; cnt += (int)h[j]; }
        int inc = cnt;
#pragma unroll
        for (int off = 1; off < 64; off <<= 1) {
            const int nv = __shfl_up(inc, off);
            if (lane >= off) inc += nv;
        }
        const int pre = inc - cnt;
        const bool found = (pre < R && R <= inc);
        unsigned pk = 0;
        if (found) {
            int c = pre, bb = -1, cb = 0; unsigned hbv = 0;
#pragma unroll
            for (int j = 0; j < 4; ++j) {
                if (bb < 0) {
                    if (c + (int)h[j] >= R) { bb = lane * 4 + j; hbv = h[j]; cb = c; }
                    else c += (int)h[j];
                }
            }
            pk = (unsigned)bb | ((unsigned)cb << 8) | (hbv << 16);
        }
        const unsigned long long fm = __ballot(found);
        pk = (unsigned)__shfl((int)pk, __ffsll(fm) - 1);
        const int bbin = (int)(pk & 255u);
        const int cb   = (int)((pk >> 8) & 255u);
        const int hb   = (int)(pk >> 16);
        const int need = R - cb;
        unsigned nnam = 0u;
#pragma unroll
        for (int i = 0; i < 16; ++i) {
            if (bin[i] < bbin) sm |= 1u << i;
            else if (bin[i] == bbin) nnam |= 1u << i;
        }
        if (hb == need && bbin != 255) {
            sm |= nnam; R = 0; do_hist = false;
        } else {
            nam = nnam; R = need;
            if (R <= 4 || shift == 0) do_hist = false;
            else {
                base += (unsigned)bbin << shift;
                shift = shift > 8 ? shift - 8 : 0;
            }
        }
    }

#pragma unroll 1
    while (R > 0) {
        unsigned lmin = 0xFFFFFFFFu;
#pragma unroll
        for (int i = 0; i < 16; ++i)
            if ((nam >> i) & 1) lmin = min(lmin, bits[i]);
        unsigned vmin = lmin;
#pragma unroll
        for (int off = 1; off < 64; off <<= 1)
            vmin = min(vmin, (unsigned)__shfl_xor((int)vmin, off));
        unsigned eq = 0u;
#pragma unroll
        for (int i = 0; i < 16; ++i)
            if (((nam >> i) & 1) && bits[i] == vmin) eq |= 1u << i;
        int tot = __popc(eq);
#pragma unroll
        for (int off = 1; off < 64; off <<= 1) tot += __shfl_xor(tot, off);
        if (tot <= R) {
            sm |= eq; nam &= ~eq; R -= tot;
        } else {
#pragma unroll
            for (int i = 0; i < 16; ++i) {
                if (R > 0) {
                    const bool c2 = (eq >> i) & 1;
                    const unsigned long long mb = __ballot(c2);
                    const int t2 = (int)__popcll(mb);
                    if (t2 <= R) { if (c2) sm |= 1u << i; R -= t2; }
                    else {
                        const unsigned long long lower = mb & ((1ull << lane) - 1ull);
                        if (c2 && (int)__popcll(lower) < R) sm |= 1u << i;
                        R = 0;
                    }
                }
            }
        }
    }

    // emit: ballot-prefix compaction
    int* out = nbr + (size_t)(cloud * PPTS + pl0 + r) * KNB;
    int tot = 0;
#pragma unroll
    for (int i = 0; i < 16; ++i) {
        const bool c2 = (sm >> i) & 1;
        const unsigned long long mb = __ballot(c2);
        if (c2) {
            const int slot = tot + (int)__popcll(mb & ((1ull << lane) - 1ull));
            if (slot < KNB) out[slot] = cloud * PPTS + lane + i * 64;
        }
        tot += (int)__popcll(mb);
    }
    if (lane == 0)
        for (int s = tot; s < KNB; ++s) out[s] = cloud * PPTS + pl0 + r;
}

// ---------------------------------------------------------------------------
// Edge GEMM: A = x @ (W_top - W_bot) + b ; Bm = x @ W_bot
// ---------------------------------------------------------------------------
template<int F, int FO>
__global__ __launch_bounds__(256) void edge_gemm_kernel(const float* __restrict__ x,
                                                        const float* __restrict__ W,
                                                        const float* __restrict__ bias,
                                                        float* __restrict__ A,
                                                        float* __restrict__ Bm) {
    constexpr int RT  = 16;
    constexpr int RS  = 256 / FO;
    constexpr int RPT = RT / RS;
    __shared__ float xs[RT][F];
    const int tid = threadIdx.x;
    const int n0  = blockIdx.x * RT;
    for (int i = tid; i < RT * F; i += 256)
        xs[i / F][i % F] = x[(size_t)n0 * F + i];
    __syncthreads();

    const int o  = tid % FO;
    const int r0 = tid / FO;
    float accA[RPT], accB[RPT];
#pragma unroll
    for (int i = 0; i < RPT; ++i) { accA[i] = 0.f; accB[i] = 0.f; }

    for (int f = 0; f < F; ++f) {
        const float wt = W[(size_t)f * FO + o];
        const float wb = W[(size_t)(F + f) * FO + o];
        const float wd = wt - wb;
#pragma unroll
        for (int i = 0; i < RPT; ++i) {
            const float xv = xs[r0 + i * RS][f];
            accA[i] = fmaf(xv, wd, accA[i]);
            accB[i] = fmaf(xv, wb, accB[i]);
        }
    }
    const float bo = bias[o];
#pragma unroll
    for (int i = 0; i < RPT; ++i) {
        const size_t row = (size_t)(n0 + r0 + i * RS);
        A[row * FO + o]  = accA[i] + bo;
        Bm[row * FO + o] = accB[i];
    }
}

// ---------------------------------------------------------------------------
// Combine (float4, R10-proven): x_out = relu(A + max_k Bm[nbr])
// ---------------------------------------------------------------------------
template<int FO>
__global__ __launch_bounds__(256) void combine_kernel(const float* __restrict__ A,
                                                      const float* __restrict__ Bm,
                                                      const int* __restrict__ nbr,
                                                      float* __restrict__ xout) {
    constexpr int FO4 = FO / 4;
    const int idx = blockIdx.x * 256 + threadIdx.x;   // over N*FO4
    const int n  = idx / FO4;
    const int o4 = idx % FO4;
    const int* nb = nbr + (size_t)n * KNB;
    const float4* B4 = reinterpret_cast<const float4*>(Bm);
    float4 mx = make_float4(-FLT_MAX, -FLT_MAX, -FLT_MAX, -FLT_MAX);
#pragma unroll 8
    for (int k = 0; k < KNB; ++k) {
        const float4 v = B4[(size_t)nb[k] * FO4 + o4];
        mx.x = fmaxf(mx.x, v.x); mx.y = fmaxf(mx.y, v.y);
        mx.z = fmaxf(mx.z, v.z); mx.w = fmaxf(mx.w, v.w);
    }
    const float4 a = reinterpret_cast<const float4*>(A)[idx];
    float4 rr;
    rr.x = fmaxf(a.x + mx.x, 0.f);
    rr.y = fmaxf(a.y + mx.y, 0.f);
    rr.z = fmaxf(a.z + mx.z, 0.f);
    rr.w = fmaxf(a.w + mx.w, 0.f);
    reinterpret_cast<float4*>(xout)[idx] = rr;
}

// ---------------------------------------------------------------------------
// Classifier + loss
// ---------------------------------------------------------------------------
__global__ __launch_bounds__(256) void classifier_kernel(const float* __restrict__ x,
                                                         const float* __restrict__ Wc,
                                                         const float* __restrict__ bc,
                                                         const int* __restrict__ target,
                                                         float* __restrict__ probs,
                                                         float* __restrict__ lossbuf) {
    const int tid = threadIdx.x;
    const int lane = tid & 63;
    const int n = blockIdx.x * 4 + (tid >> 6);
    const float* xr = x + (size_t)n * 256;
    float logit = -FLT_MAX;
    if (lane < NCLS) {
        float acc = bc[lane];
        for (int f = 0; f < 256; ++f)
            acc = fmaf(xr[f], Wc[f * NCLS + lane], acc);
        logit = acc;
    }
    float m = logit;
#pragma unroll
    for (int off = 32; off; off >>= 1) m = fmaxf(m, __shfl_xor(m, off));
    const float e = (lane < NCLS) ? __expf(logit - m) : 0.f;
    float s = e;
#pragma unroll
    for (int off = 32; off; off >>= 1) s += __shfl_xor(s, off);
    if (lane < NCLS) probs[(size_t)n * NCLS + lane] = e / s;
    const float lt = __shfl(logit, target[n]);
    if (lane == 0) lossbuf[n] = logf(s) - (lt - m);
}

__global__ __launch_bounds__(256) void loss_reduce_kernel(const float* __restrict__ lossbuf,
                                                          float* __restrict__ out) {
    __shared__ float s[256];
    float acc = 0.f;
    for (int i = threadIdx.x; i < NPTS; i += 256) acc += lossbuf[i];
    s[threadIdx.x] = acc;
    __syncthreads();
    for (int off = 128; off; off >>= 1) {
        if (threadIdx.x < off) s[threadIdx.x] += s[threadIdx.x + off];
        __syncthreads();
    }
    if (threadIdx.x == 0) out[0] = s[0] / (float)NPTS;
}

extern "C" void kernel_launch(void* const* d_in, const int* in_sizes, int n_in,
                              void* d_out, int out_size, void* d_ws, size_t ws_size,
                              hipStream_t stream) {
    (void)in_sizes; (void)n_in; (void)out_size; (void)ws_size;
    const float* x_in   = (const float*)d_in[0];
    const int*   target = (const int*)d_in[2];
    const float* W1 = (const float*)d_in[3];
    const float* b1 = (const float*)d_in[4];
    const float* W2 = (const float*)d_in[5];
    const float* b2 = (const float*)d_in[6];
    const float* W3 = (const float*)d_in[7];
    const float* b3 = (const float*)d_in[8];
    const float* Wc = (const float*)d_in[9];
    const float* bc = (const float*)d_in[10];

    // proven-safe window [0, 50MB+64KB):
    //   X [0,16M) | A [16,32M) | Bm [32,48M) | nbr [48,50M) | lossbuf [50M,+64K)
    //   xT [32,40M) + qn [40M,+64K) alias dead-Bm during kNN phase (R9-proven)
    char* ws = (char*)d_ws;
    float* X       = (float*)(ws);
    float* A       = (float*)(ws + (size_t)16 * 1024 * 1024);
    float* Bm      = (float*)(ws + (size_t)32 * 1024 * 1024);
    float* xT      = (float*)(ws + (size_t)32 * 1024 * 1024);
    float* qn      = (float*)(ws + (size_t)40 * 1024 * 1024);
    int*   nbr     = (int*)  (ws + (size_t)48 * 1024 * 1024);
    float* lossbuf = (float*)(ws + (size_t)50 * 1024 * 1024);

    float* outF  = (float*)d_out;
    float* probs = outF + 1;

    // ---- layer 1 (3 -> 64) ----
    xpose_kernel<3><<<NPTS / 256, 256, 0, stream>>>(x_in, xT, qn);
    knn_kernel<3><<<NPTS / RPB, 512, 0, stream>>>(x_in, xT, qn, nbr);
    edge_gemm_kernel<3, 64><<<NPTS / 16, 256, 0, stream>>>(x_in, W1, b1, A, Bm);
    combine_kernel<64><<<NPTS * 16 / 256, 256, 0, stream>>>(A, Bm, nbr, X);

    // ---- layer 2 (64 -> 128) ----
    xpose_kernel<64><<<NPTS / 256, 256, 0, stream>>>(X, xT, qn);
    knn_kernel<64><<<NPTS / RPB, 512, 0, stream>>>(X, xT, qn, nbr);
    edge_gemm_kernel<64, 128><<<NPTS / 16, 256, 0, stream>>>(X, W2, b2, A, Bm);
    combine_kernel<128><<<NPTS * 32 / 256, 256, 0, stream>>>(A, Bm, nbr, X);

    // ---- layer 3 (128 -> 256) ----
    xpose_kernel<128><<<NPTS / 256, 256, 0, stream>>>(X, xT, qn);
    knn_kernel<128><<<NPTS / RPB, 512, 0, stream>>>(X, xT, qn, nbr);
    edge_gemm_kernel<128, 256><<<NPTS / 16, 256, 0, stream>>>(X, W3, b3, A, Bm);
    combine_kernel<256><<<NPTS * 64 / 256, 256, 0, stream>>>(A, Bm, nbr, X);

    // ---- classifier + loss ----
    classifier_kernel<<<NPTS / 4, 256, 0, stream>>>(X, Wc, bc, target, probs, lossbuf);
    loss_reduce_kernel<<<1, 256, 0, stream>>>(lossbuf, outF);
}

// Round 12
// 406.296 us; speedup vs baseline: 2.3970x; 1.0101x over previous
//
#include <hip/hip_runtime.h>
#include <float.h>
#include <math.h>

#define BCLOUDS 16
#define PPTS    1024
#define NPTS    (BCLOUDS * PPTS)
#define KNB     32
#define NCLS    40
#define RPB     8                  // rows per knn block (= waves per block)
#define NBIN    256
#define HPADW   (NBIN + NBIN / 16)
#define SELFM   0xFFFFFFFFu        // self marker: above every real distance bit pattern

__device__ __forceinline__ int hidx(int b) { return b + (b >> 4); }

// ---------------------------------------------------------------------------
// Transpose + norms: xT[cloud][f][p] = x[cloud*1024+p][f]; qn[p] = |x_p|^2
// ---------------------------------------------------------------------------
template<int F>
__global__ __launch_bounds__(256) void xpose_kernel(const float* __restrict__ x,
                                                    float* __restrict__ xT,
                                                    float* __restrict__ qn) {
    const int p = blockIdx.x * 256 + threadIdx.x;   // global point id
    const int cloud = p >> 10, pl = p & 1023;
    const float* xr = x + (size_t)p * F;
    float* xTc = xT + (size_t)cloud * F * PPTS;
    float s = 0.f;
    for (int f = 0; f < F; ++f) {
        const float v = xr[f];
        s = fmaf(v, v, s);
        xTc[(size_t)f * PPTS + pl] = v;             // coalesced along pl
    }
    qn[p] = s;
}

// ---------------------------------------------------------------------------
// Fused kNN: 8 rows/block, 512 threads.
// XCD swizzle: blocks with bid%8==k handle clouds {k, k+8} -> each XCD's L2
// holds only its 2 clouds (~2MB < 4MB) -> xT/x L2-resident, no cross-XCD thrash.
// Distance: candidates 2*tid,2*tid+1 via float2 loads from xT (coalesced,
// half the load instructions). Selection = R6-proven verbatim.
// ---------------------------------------------------------------------------
template<int F>
__global__ __launch_bounds__(512, 6) void knn_kernel(const float* __restrict__ x,
                                                     const float* __restrict__ xT,
                                                     const float* __restrict__ qn,
                                                     int* __restrict__ nbr) {
    __shared__ unsigned dmat[RPB][PPTS];
    __shared__ float    xp[RPB][F];
    __shared__ float    rn[RPB];
    __shared__ unsigned hist[RPB][HPADW];

    const int tid   = threadIdx.x;
    const int lane  = tid & 63;
    const int wave  = tid >> 6;            // 0..7
    // XCD-affine remap (bijective over 2048 blocks; perf-only assumption that
    // consecutive blockIdx round-robin XCDs — correctness independent of it)
    const int bid   = blockIdx.x;
    const int cloud = (bid & 7) + 8 * (bid >> 10);
    const int pl0   = ((bid >> 3) & 127) * RPB;

    // query rows (8 rows of x, row-major) + row norms
    const float* xc = x + (size_t)cloud * PPTS * F;
    for (int i = tid; i < RPB * F; i += 512)
        xp[i / F][i % F] = xc[(size_t)(pl0 + i / F) * F + (i % F)];
    __syncthreads();
    if (tid < RPB) {
        float s = 0.f;
        for (int f = 0; f < F; ++f) { const float v = xp[tid][f]; s = fmaf(v, v, s); }
        rn[tid] = s;
    }
    __syncthreads();

    // ---- distances: candidates q = 2*tid, 2*tid+1, float2 loads from xT ----
    const float* xTc = xT + (size_t)cloud * F * PPTS;
    const float2 qv = *reinterpret_cast<const float2*>(&qn[cloud * PPTS + 2 * tid]);

    float acc[RPB][2];
#pragma unroll
    for (int r = 0; r < RPB; ++r) { acc[r][0] = 0.f; acc[r][1] = 0.f; }

#pragma unroll 4
    for (int f = 0; f < F; ++f) {
        const float2 v = *reinterpret_cast<const float2*>(&xTc[(size_t)f * PPTS + 2 * tid]);
#pragma unroll
        for (int r = 0; r < RPB; ++r) {
            const float xv = xp[r][f];
            acc[r][0] = fmaf(v.x, xv, acc[r][0]);
            acc[r][1] = fmaf(v.y, xv, acc[r][1]);
        }
    }
#pragma unroll
    for (int c = 0; c < 2; ++c) {
        const int q = 2 * tid + c;
        const float qvc = c ? qv.y : qv.x;
#pragma unroll
        for (int r = 0; r < RPB; ++r) {
            float d2 = rn[r] + qvc - 2.f * acc[r][c];
            d2 = fmaxf(d2, 0.f);
            dmat[r][q] = (q == pl0 + r) ? SELFM : __float_as_uint(d2);
        }
    }
    __syncthreads();

    // ---- selection (R6-proven verbatim): wave w handles row w ----
    unsigned* hw = hist[wave];
    const int r = wave;
    unsigned bits[16];
#pragma unroll
    for (int i = 0; i < 16; ++i) bits[i] = dmat[r][lane + i * 64];

    unsigned m = bits[0];
#pragma unroll
    for (int i = 1; i < 16; ++i) m = min(m, bits[i]);
    unsigned gmin = m;
    unsigned tmax = (lane < 32) ? m : 0u;
#pragma unroll
    for (int off = 1; off < 64; off <<= 1) {
        gmin = min(gmin, (unsigned)__shfl_xor((int)gmin, off));
        tmax = max(tmax, (unsigned)__shfl_xor((int)tmax, off));
    }

    unsigned sm = 0u, nam = 0xFFFFu;
    int R = KNB;
    unsigned base = gmin;
    int shift = 0;
    bool do_hist = tmax > gmin;
    if (do_hist) {
        const unsigned span = tmax - gmin;
        const int lg = 31 - __clz(span);
        shift = lg > 7 ? lg - 7 : 0;
    }

#pragma unroll 1
    for (int pass = 0; pass < 2 && do_hist; ++pass) {
        int bin[16];
#pragma unroll
        for (int j = 0; j < 5; ++j) { const int k2 = lane + j * 64; if (k2 < HPADW) hw[k2] = 0u; }
#pragma unroll
        for (int i = 0; i < 16; ++i) {
            if ((nam >> i) & 1) {
                const unsigned d = bits[i] - base;
                int b = (int)(d >> shift);
                b = b > 255 ? 255 : b;                // junk/self clamp to 255
                bin[i] = b;
                atomicAdd(&hw[hidx(b)], 1u);
            } else bin[i] = 256;
        }
        unsigned h[4];
        int cnt = 0;
#pragma unroll
        for (int j = 0; j < 4; ++j) { h[j] = hw[hidx(lane * 4 + j)]; cnt += (int)h[j]; }
        int inc = cnt;
#pragma unroll
        for (int off = 1; off < 64; off <<= 1) {
            const int nv = __shfl_up(inc, off);
            if (lane >= off) inc += nv;
        }
        const int pre = inc - cnt;
        const bool found = (pre < R && R <= inc);
        unsigned pk = 0;
        if (found) {
            int c = pre, bb = -1, cb = 0; unsigned hbv = 0;
#pragma unroll
            for (int j = 0; j < 4; ++j) {
                if (bb < 0) {
                    if (c + (int)h[j] >= R) { bb = lane * 4 + j; hbv = h[j]; cb = c; }
                    else c += (int)h[j];
                }
            }
            pk = (unsigned)bb | ((unsigned)cb << 8) | (hbv << 16);
        }
        const unsigned long long fm = __ballot(found);
        pk = (unsigned)__shfl((int)pk, __ffsll(fm) - 1);
        const int bbin = (int)(pk & 255u);
        const int cb   = (int)((pk >> 8) & 255u);
        const int hb   = (int)(pk >> 16);
        const int need = R - cb;
        unsigned nnam = 0u;
#pragma unroll
        for (int i = 0; i < 16; ++i) {
            if (bin[i] < bbin) sm |= 1u << i;
            else if (bin[i] == bbin) nnam |= 1u << i;
        }
        if (hb == need && bbin != 255) {
            sm |= nnam; R = 0; do_hist = false;
        } else {
            nam = nnam; R = need;
            if (R <= 4 || shift == 0) do_hist = false;
            else {
                base += (unsigned)bbin << shift;
                shift = shift > 8 ? shift - 8 : 0;
            }
        }
    }

#pragma unroll 1
    while (R > 0) {
        unsigned lmin = 0xFFFFFFFFu;
#pragma unroll
        for (int i = 0; i < 16; ++i)
            if ((nam >> i) & 1) lmin = min(lmin, bits[i]);
        unsigned vmin = lmin;
#pragma unroll
        for (int off = 1; off < 64; off <<= 1)
            vmin = min(vmin, (unsigned)__shfl_xor((int)vmin, off));
        unsigned eq = 0u;
#pragma unroll
        for (int i = 0; i < 16; ++i)
            if (((nam >> i) & 1) && bits[i] == vmin) eq |= 1u << i;
        int tot = __popc(eq);
#pragma unroll
        for (int off = 1; off < 64; off <<= 1) tot += __shfl_xor(tot, off);
        if (tot <= R) {
            sm |= eq; nam &= ~eq; R -= tot;
        } else {
#pragma unroll
            for (int i = 0; i < 16; ++i) {
                if (R > 0) {
                    const bool c2 = (eq >> i) & 1;
                    const unsigned long long mb = __ballot(c2);
                    const int t2 = (int)__popcll(mb);
                    if (t2 <= R) { if (c2) sm |= 1u << i; R -= t2; }
                    else {
                        const unsigned long long lower = mb & ((1ull << lane) - 1ull);
                        if (c2 && (int)__popcll(lower) < R) sm |= 1u << i;
                        R = 0;
                    }
                }
            }
        }
    }

    // emit: ballot-prefix compaction
    int* out = nbr + (size_t)(cloud * PPTS + pl0 + r) * KNB;
    int tot = 0;
#pragma unroll
    for (int i = 0; i < 16; ++i) {
        const bool c2 = (sm >> i) & 1;
        const unsigned long long mb = __ballot(c2);
        if (c2) {
            const int slot = tot + (int)__popcll(mb & ((1ull << lane) - 1ull));
            if (slot < KNB) out[slot] = cloud * PPTS + lane + i * 64;
        }
        tot += (int)__popcll(mb);
    }
    if (lane == 0)
        for (int s = tot; s < KNB; ++s) out[s] = cloud * PPTS + pl0 + r;
}

// ---------------------------------------------------------------------------
// Edge GEMM: A = x @ (W_top - W_bot) + b ; Bm = x @ W_bot
// ---------------------------------------------------------------------------
template<int F, int FO>
__global__ __launch_bounds__(256) void edge_gemm_kernel(const float* __restrict__ x,
                                                        const float* __restrict__ W,
                                                        const float* __restrict__ bias,
                                                        float* __restrict__ A,
                                                        float* __restrict__ Bm) {
    constexpr int RT  = 16;
    constexpr int RS  = 256 / FO;
    constexpr int RPT = RT / RS;
    __shared__ float xs[RT][F];
    const int tid = threadIdx.x;
    const int n0  = blockIdx.x * RT;
    for (int i = tid; i < RT * F; i += 256)
        xs[i / F][i % F] = x[(size_t)n0 * F + i];
    __syncthreads();

    const int o  = tid % FO;
    const int r0 = tid / FO;
    float accA[RPT], accB[RPT];
#pragma unroll
    for (int i = 0; i < RPT; ++i) { accA[i] = 0.f; accB[i] = 0.f; }

    for (int f = 0; f < F; ++f) {
        const float wt = W[(size_t)f * FO + o];
        const float wb = W[(size_t)(F + f) * FO + o];
        const float wd = wt - wb;
#pragma unroll
        for (int i = 0; i < RPT; ++i) {
            const float xv = xs[r0 + i * RS][f];
            accA[i] = fmaf(xv, wd, accA[i]);
            accB[i] = fmaf(xv, wb, accB[i]);
        }
    }
    const float bo = bias[o];
#pragma unroll
    for (int i = 0; i < RPT; ++i) {
        const size_t row = (size_t)(n0 + r0 + i * RS);
        A[row * FO + o]  = accA[i] + bo;
        Bm[row * FO + o] = accB[i];
    }
}

// ---------------------------------------------------------------------------
// Combine (float4): x_out = relu(A + max_k Bm[nbr])
// ---------------------------------------------------------------------------
template<int FO>
__global__ __launch_bounds__(256) void combine_kernel(const float* __restrict__ A,
                                                      const float* __restrict__ Bm,
                                                      const int* __restrict__ nbr,
                                                      float* __restrict__ xout) {
    constexpr int FO4 = FO / 4;
    const int idx = blockIdx.x * 256 + threadIdx.x;   // over N*FO4
    const int n  = idx / FO4;
    const int o4 = idx % FO4;
    const int* nb = nbr + (size_t)n * KNB;
    const float4* B4 = reinterpret_cast<const float4*>(Bm);
    float4 mx = make_float4(-FLT_MAX, -FLT_MAX, -FLT_MAX, -FLT_MAX);
#pragma unroll 8
    for (int k = 0; k < KNB; ++k) {
        const float4 v = B4[(size_t)nb[k] * FO4 + o4];
        mx.x = fmaxf(mx.x, v.x); mx.y = fmaxf(mx.y, v.y);
        mx.z = fmaxf(mx.z, v.z); mx.w = fmaxf(mx.w, v.w);
    }
    const float4 a = reinterpret_cast<const float4*>(A)[idx];
    float4 rr;
    rr.x = fmaxf(a.x + mx.x, 0.f);
    rr.y = fmaxf(a.y + mx.y, 0.f);
    rr.z = fmaxf(a.z + mx.z, 0.f);
    rr.w = fmaxf(a.w + mx.w, 0.f);
    reinterpret_cast<float4*>(xout)[idx] = rr;
}

// ---------------------------------------------------------------------------
// Classifier + loss
// ---------------------------------------------------------------------------
__global__ __launch_bounds__(256) void classifier_kernel(const float* __restrict__ x,
                                                         const float* __restrict__ Wc,
                                                         const float* __restrict__ bc,
                                                         const int* __restrict__ target,
                                                         float* __restrict__ probs,
                                                         float* __restrict__ lossbuf) {
    const int tid = threadIdx.x;
    const int lane = tid & 63;
    const int n = blockIdx.x * 4 + (tid >> 6);
    const float* xr = x + (size_t)n * 256;
    float logit = -FLT_MAX;
    if (lane < NCLS) {
        float acc = bc[lane];
        for (int f = 0; f < 256; ++f)
            acc = fmaf(xr[f], Wc[f * NCLS + lane], acc);
        logit = acc;
    }
    float m = logit;
#pragma unroll
    for (int off = 32; off; off >>= 1) m = fmaxf(m, __shfl_xor(m, off));
    const float e = (lane < NCLS) ? __expf(logit - m) : 0.f;
    float s = e;
#pragma unroll
    for (int off = 32; off; off >>= 1) s += __shfl_xor(s, off);
    if (lane < NCLS) probs[(size_t)n * NCLS + lane] = e / s;
    const float lt = __shfl(logit, target[n]);
    if (lane == 0) lossbuf[n] = logf(s) - (lt - m);
}

__global__ __launch_bounds__(256) void loss_reduce_kernel(const float* __restrict__ lossbuf,
                                                          float* __restrict__ out) {
    __shared__ float s[256];
    float acc = 0.f;
    for (int i = threadIdx.x; i < NPTS; i += 256) acc += lossbuf[i];
    s[threadIdx.x] = acc;
    __syncthreads();
    for (int off = 128; off; off >>= 1) {
        if (threadIdx.x < off) s[threadIdx.x] += s[threadIdx.x + off];
        __syncthreads();
    }
    if (threadIdx.x == 0) out[0] = s[0] / (float)NPTS;
}

extern "C" void kernel_launch(void* const* d_in, const int* in_sizes, int n_in,
                              void* d_out, int out_size, void* d_ws, size_t ws_size,
                              hipStream_t stream) {
    (void)in_sizes; (void)n_in; (void)out_size; (void)ws_size;
    const float* x_in   = (const float*)d_in[0];
    const int*   target = (const int*)d_in[2];
    const float* W1 = (const float*)d_in[3];
    const float* b1 = (const float*)d_in[4];
    const float* W2 = (const float*)d_in[5];
    const float* b2 = (const float*)d_in[6];
    const float* W3 = (const float*)d_in[7];
    const float* b3 = (const float*)d_in[8];
    const float* Wc = (const float*)d_in[9];
    const float* bc = (const float*)d_in[10];

    // proven-safe window [0, 50MB+64KB):
    //   X [0,16M) | A [16,32M) | Bm [32,48M) | nbr [48,50M) | lossbuf [50M,+64K)
    //   xT [32,40M) + qn [40M,+64K) alias dead-Bm during kNN phase
    char* ws = (char*)d_ws;
    float* X       = (float*)(ws);
    float* A       = (float*)(ws + (size_t)16 * 1024 * 1024);
    float* Bm      = (float*)(ws + (size_t)32 * 1024 * 1024);
    float* xT      = (float*)(ws + (size_t)32 * 1024 * 1024);
    float* qn      = (float*)(ws + (size_t)40 * 1024 * 1024);
    int*   nbr     = (int*)  (ws + (size_t)48 * 1024 * 1024);
    float* lossbuf = (float*)(ws + (size_t)50 * 1024 * 1024);

    float* outF  = (float*)d_out;
    float* probs = outF + 1;

    // ---- layer 1 (3 -> 64) ----
    xpose_kernel<3><<<NPTS / 256, 256, 0, stream>>>(x_in, xT, qn);
    knn_kernel<3><<<NPTS / RPB, 512, 0, stream>>>(x_in, xT, qn, nbr);
    edge_gemm_kernel<3, 64><<<NPTS / 16, 256, 0, stream>>>(x_in, W1, b1, A, Bm);
    combine_kernel<64><<<NPTS * 16 / 256, 256, 0, stream>>>(A, Bm, nbr, X);

    // ---- layer 2 (64 -> 128) ----
    xpose_kernel<64><<<NPTS / 256, 256, 0, stream>>>(X, xT, qn);
    knn_kernel<64><<<NPTS / RPB, 512, 0, stream>>>(X, xT, qn, nbr);
    edge_gemm_kernel<64, 128><<<NPTS / 16, 256, 0, stream>>>(X, W2, b2, A, Bm);
    combine_kernel<128><<<NPTS * 32 / 256, 256, 0, stream>>>(A, Bm, nbr, X);

    // ---- layer 3 (128 -> 256) ----
    xpose_kernel<128><<<NPTS / 256, 256, 0, stream>>>(X, xT, qn);
    knn_kernel<128><<<NPTS / RPB, 512, 0, stream>>>(X, xT, qn, nbr);
    edge_gemm_kernel<128, 256><<<NPTS / 16, 256, 0, stream>>>(X, W3, b3, A, Bm);
    combine_kernel<256><<<NPTS * 64 / 256, 256, 0, stream>>>(A, Bm, nbr, X);

    // ---- classifier + loss ----
    classifier_kernel<<<NPTS / 4, 256, 0, stream>>>(X, Wc, bc, target, probs, lossbuf);
    loss_reduce_kernel<<<1, 256, 0, stream>>>(lossbuf, outF);
}

// Round 13
// 396.474 us; speedup vs baseline: 2.4564x; 1.0248x over previous
//
#include <hip/hip_runtime.h>
#include <float.h>
#include <math.h>

#define BCLOUDS 16
#define PPTS    1024
#define NPTS    (BCLOUDS * PPTS)
#define KNB     32
#define NCLS    40
#define RPB     4                  // rows per knn block (= waves per block)
#define NBIN    256
#define HPADW   (NBIN + NBIN / 16)
#define SELFM   0xFFFFFFFFu        // self marker: above every real distance bit pattern

__device__ __forceinline__ int hidx(int b) { return b + (b >> 4); }

// ---------------------------------------------------------------------------
// Transpose + norms: xT[cloud][f][p] = x[cloud*1024+p][f]; qn[p] = |x_p|^2
// ---------------------------------------------------------------------------
template<int F>
__global__ __launch_bounds__(256) void xpose_kernel(const float* __restrict__ x,
                                                    float* __restrict__ xT,
                                                    float* __restrict__ qn) {
    const int p = blockIdx.x * 256 + threadIdx.x;   // global point id
    const int cloud = p >> 10, pl = p & 1023;
    const float* xr = x + (size_t)p * F;
    float* xTc = xT + (size_t)cloud * F * PPTS;
    float s = 0.f;
    for (int f = 0; f < F; ++f) {
        const float v = xr[f];
        s = fmaf(v, v, s);
        xTc[(size_t)f * PPTS + pl] = v;             // coalesced along pl
    }
    qn[p] = s;
}

// ---------------------------------------------------------------------------
// Fused kNN v2: 4 rows/block, 256 threads, LDS ~22.5KB -> 6 blocks/CU
// (24 waves) so selection latency is occupancy-hidden (R9/R10 split-kernel
// evidence: same logic at high occupancy = ~20us/8192 rows).
// XCD swizzle keeps each cloud's xT/x in its XCD L2 (R12: FETCH 37->8.3MB).
// Distance: candidates 4*tid+c, float4 xT loads, xp via ds_read_b128 per f4.
// Selection = R6-proven verbatim (wave w -> row w).
// ---------------------------------------------------------------------------
template<int F>
__global__ __launch_bounds__(256, 6) void knn_kernel(const float* __restrict__ x,
                                                     const float* __restrict__ xT,
                                                     const float* __restrict__ qn,
                                                     int* __restrict__ nbr) {
    __shared__ unsigned dmat[RPB][PPTS];
    __shared__ float    xp[RPB][F];
    __shared__ float    rn[RPB];
    __shared__ unsigned hist[RPB][HPADW];

    const int tid   = threadIdx.x;
    const int lane  = tid & 63;
    const int wave  = tid >> 6;            // 0..3
    // XCD-affine remap over 4096 blocks (bijective): blocks with bid%8==k
    // handle clouds {k, k+8}; rowblk = (bid>>3)&255
    const int bid   = blockIdx.x;
    const int cloud = (bid & 7) + 8 * (bid >> 11);
    const int pl0   = ((bid >> 3) & 255) * RPB;

    // query rows (4 rows of x, row-major) + row norms
    const float* xc = x + (size_t)cloud * PPTS * F;
    for (int i = tid; i < RPB * F; i += 256)
        xp[i / F][i % F] = xc[(size_t)(pl0 + i / F) * F + (i % F)];
    __syncthreads();
    if (tid < RPB) {
        float s = 0.f;
        for (int f = 0; f < F; ++f) { const float v = xp[tid][f]; s = fmaf(v, v, s); }
        rn[tid] = s;
    }
    __syncthreads();

    // ---- distances: candidates q = 4*tid+c, float4 loads from xT ----
    const float* xTc = xT + (size_t)cloud * F * PPTS;
    const float4 qv = *reinterpret_cast<const float4*>(&qn[cloud * PPTS + 4 * tid]);

    float acc[RPB][4];
#pragma unroll
    for (int r = 0; r < RPB; ++r)
#pragma unroll
        for (int c = 0; c < 4; ++c) acc[r][c] = 0.f;

    if constexpr (F % 4 == 0) {
#pragma unroll 2
        for (int f4 = 0; f4 < F / 4; ++f4) {
            float4 vf[4];   // vf[j] = feature (4*f4+j) for candidates 4*tid..4*tid+3
#pragma unroll
            for (int j = 0; j < 4; ++j)
                vf[j] = *reinterpret_cast<const float4*>(&xTc[(size_t)(4 * f4 + j) * PPTS + 4 * tid]);
            float4 xr[RPB]; // xr[r] = features 4*f4..4*f4+3 of query row r (ds_read_b128)
#pragma unroll
            for (int r = 0; r < RPB; ++r) xr[r] = *reinterpret_cast<const float4*>(&xp[r][4 * f4]);
#pragma unroll
            for (int r = 0; r < RPB; ++r) {
                acc[r][0] = fmaf(vf[0].x, xr[r].x, acc[r][0]);
                acc[r][1] = fmaf(vf[0].y, xr[r].x, acc[r][1]);
                acc[r][2] = fmaf(vf[0].z, xr[r].x, acc[r][2]);
                acc[r][3] = fmaf(vf[0].w, xr[r].x, acc[r][3]);
                acc[r][0] = fmaf(vf[1].x, xr[r].y, acc[r][0]);
                acc[r][1] = fmaf(vf[1].y, xr[r].y, acc[r][1]);
                acc[r][2] = fmaf(vf[1].z, xr[r].y, acc[r][2]);
                acc[r][3] = fmaf(vf[1].w, xr[r].y, acc[r][3]);
                acc[r][0] = fmaf(vf[2].x, xr[r].z, acc[r][0]);
                acc[r][1] = fmaf(vf[2].y, xr[r].z, acc[r][1]);
                acc[r][2] = fmaf(vf[2].z, xr[r].z, acc[r][2]);
                acc[r][3] = fmaf(vf[2].w, xr[r].z, acc[r][3]);
                acc[r][0] = fmaf(vf[3].x, xr[r].w, acc[r][0]);
                acc[r][1] = fmaf(vf[3].y, xr[r].w, acc[r][1]);
                acc[r][2] = fmaf(vf[3].z, xr[r].w, acc[r][2]);
                acc[r][3] = fmaf(vf[3].w, xr[r].w, acc[r][3]);
            }
        }
    } else {
        for (int f = 0; f < F; ++f) {
            const float4 v = *reinterpret_cast<const float4*>(&xTc[(size_t)f * PPTS + 4 * tid]);
#pragma unroll
            for (int r = 0; r < RPB; ++r) {
                const float xv = xp[r][f];
                acc[r][0] = fmaf(v.x, xv, acc[r][0]);
                acc[r][1] = fmaf(v.y, xv, acc[r][1]);
                acc[r][2] = fmaf(v.z, xv, acc[r][2]);
                acc[r][3] = fmaf(v.w, xv, acc[r][3]);
            }
        }
    }
#pragma unroll
    for (int r = 0; r < RPB; ++r) {
        uint4 wv;
        float d2;
        d2 = fmaxf(rn[r] + qv.x - 2.f * acc[r][0], 0.f);
        wv.x = (4 * tid + 0 == pl0 + r) ? SELFM : __float_as_uint(d2);
        d2 = fmaxf(rn[r] + qv.y - 2.f * acc[r][1], 0.f);
        wv.y = (4 * tid + 1 == pl0 + r) ? SELFM : __float_as_uint(d2);
        d2 = fmaxf(rn[r] + qv.z - 2.f * acc[r][2], 0.f);
        wv.z = (4 * tid + 2 == pl0 + r) ? SELFM : __float_as_uint(d2);
        d2 = fmaxf(rn[r] + qv.w - 2.f * acc[r][3], 0.f);
        wv.w = (4 * tid + 3 == pl0 + r) ? SELFM : __float_as_uint(d2);
        *reinterpret_cast<uint4*>(&dmat[r][4 * tid]) = wv;
    }
    __syncthreads();

    // ---- selection (R6-proven verbatim): wave w handles row w ----
    unsigned* hw = hist[wave];
    const int r = wave;
    unsigned bits[16];
#pragma unroll
    for (int i = 0; i < 16; ++i) bits[i] = dmat[r][lane + i * 64];

    unsigned m = bits[0];
#pragma unroll
    for (int i = 1; i < 16; ++i) m = min(m, bits[i]);
    unsigned gmin = m;
    unsigned tmax = (lane < 32) ? m : 0u;
#pragma unroll
    for (int off = 1; off < 64; off <<= 1) {
        gmin = min(gmin, (unsigned)__shfl_xor((int)gmin, off));
        tmax = max(tmax, (unsigned)__shfl_xor((int)tmax, off));
    }

    unsigned sm = 0u, nam = 0xFFFFu;
    int R = KNB;
    unsigned base = gmin;
    int shift = 0;
    bool do_hist = tmax > gmin;
    if (do_hist) {
        const unsigned span = tmax - gmin;
        const int lg = 31 - __clz(span);
        shift = lg > 7 ? lg - 7 : 0;
    }

#pragma unroll 1
    for (int pass = 0; pass < 2 && do_hist; ++pass) {
        int bin[16];
#pragma unroll
        for (int j = 0; j < 5; ++j) { const int k2 = lane + j * 64; if (k2 < HPADW) hw[k2] = 0u; }
#pragma unroll
        for (int i = 0; i < 16; ++i) {
            if ((nam >> i) & 1) {
                const unsigned d = bits[i] - base;
                int b = (int)(d >> shift);
                b = b > 255 ? 255 : b;                // junk/self clamp to 255
                bin[i] = b;
                atomicAdd(&hw[hidx(b)], 1u);
            } else bin[i] = 256;
        }
        unsigned h[4];
        int cnt = 0;
#pragma unroll
        for (int j = 0; j < 4; ++j) { h[j] = hw[hidx(lane * 4 + j)]; cnt += (int)h[j]; }
        int inc = cnt;
#pragma unroll
        for (int off = 1; off < 64; off <<= 1) {
            const int nv = __shfl_up(inc, off);
            if (lane >= off) inc += nv;
        }
        const int pre = inc - cnt;
        const bool found = (pre < R && R <= inc);
        unsigned pk = 0;
        if (found) {
            int c = pre, bb = -1, cb = 0; unsigned hbv = 0;
#pragma unroll
            for (int j = 0; j < 4; ++j) {
                if (bb < 0) {
                    if (c + (int)h[j] >= R) { bb = lane * 4 + j; hbv = h[j]; cb = c; }
                    else c += (int)h[j];
                }
            }
            pk = (unsigned)bb | ((unsigned)cb << 8) | (hbv << 16);
        }
        const unsigned long long fm = __ballot(found);
        pk = (unsigned)__shfl((int)pk, __ffsll(fm) - 1);
        const int bbin = (int)(pk & 255u);
        const int cb   = (int)((pk >> 8) & 255u);
        const int hb   = (int)(pk >> 16);
        const int need = R - cb;
        unsigned nnam = 0u;
#pragma unroll
        for (int i = 0; i < 16; ++i) {
            if (bin[i] < bbin) sm |= 1u << i;
            else if (bin[i] == bbin) nnam |= 1u << i;
        }
        if (hb == need && bbin != 255) {
            sm |= nnam; R = 0; do_hist = false;
        } else {
            nam = nnam; R = need;
            if (R <= 4 || shift == 0) do_hist = false;
            else {
                base += (unsigned)bbin << shift;
                shift = shift > 8 ? shift - 8 : 0;
            }
        }
    }

#pragma unroll 1
    while (R > 0) {
        unsigned lmin = 0xFFFFFFFFu;
#pragma unroll
        for (int i = 0; i < 16; ++i)
            if ((nam >> i) & 1) lmin = min(lmin, bits[i]);
        unsigned vmin = lmin;
#pragma unroll
        for (int off = 1; off < 64; off <<= 1)
            vmin = min(vmin, (unsigned)__shfl_xor((int)vmin, off));
        unsigned eq = 0u;
#pragma unroll
        for (int i = 0; i < 16; ++i)
            if (((nam >> i) & 1) && bits[i] == vmin) eq |= 1u << i;
        int tot = __popc(eq);
#pragma unroll
        for (int off = 1; off < 64; off <<= 1) tot += __shfl_xor(tot, off);
        if (tot <= R) {
            sm |= eq; nam &= ~eq; R -= tot;
        } else {
#pragma unroll
            for (int i = 0; i < 16; ++i) {
                if (R > 0) {
                    const bool c2 = (eq >> i) & 1;
                    const unsigned long long mb = __ballot(c2);
                    const int t2 = (int)__popcll(mb);
                    if (t2 <= R) { if (c2) sm |= 1u << i; R -= t2; }
                    else {
                        const unsigned long long lower = mb & ((1ull << lane) - 1ull);
                        if (c2 && (int)__popcll(lower) < R) sm |= 1u << i;
                        R = 0;
                    }
                }
            }
        }
    }

    // emit: ballot-prefix compaction
    int* out = nbr + (size_t)(cloud * PPTS + pl0 + r) * KNB;
    int tot = 0;
#pragma unroll
    for (int i = 0; i < 16; ++i) {
        const bool c2 = (sm >> i) & 1;
        const unsigned long long mb = __ballot(c2);
        if (c2) {
            const int slot = tot + (int)__popcll(mb & ((1ull << lane) - 1ull));
            if (slot < KNB) out[slot] = cloud * PPTS + lane + i * 64;
        }
        tot += (int)__popcll(mb);
    }
    if (lane == 0)
        for (int s = tot; s < KNB; ++s) out[s] = cloud * PPTS + pl0 + r;
}

// ---------------------------------------------------------------------------
// Edge GEMM: A = x @ (W_top - W_bot) + b ; Bm = x @ W_bot
// ---------------------------------------------------------------------------
template<int F, int FO>
__global__ __launch_bounds__(256) void edge_gemm_kernel(const float* __restrict__ x,
                                                        const float* __restrict__ W,
                                                        const float* __restrict__ bias,
                                                        float* __restrict__ A,
                                                        float* __restrict__ Bm) {
    constexpr int RT  = 16;
    constexpr int RS  = 256 / FO;
    constexpr int RPT = RT / RS;
    __shared__ float xs[RT][F];
    const int tid = threadIdx.x;
    const int n0  = blockIdx.x * RT;
    for (int i = tid; i < RT * F; i += 256)
        xs[i / F][i % F] = x[(size_t)n0 * F + i];
    __syncthreads();

    const int o  = tid % FO;
    const int r0 = tid / FO;
    float accA[RPT], accB[RPT];
#pragma unroll
    for (int i = 0; i < RPT; ++i) { accA[i] = 0.f; accB[i] = 0.f; }

    for (int f = 0; f < F; ++f) {
        const float wt = W[(size_t)f * FO + o];
        const float wb = W[(size_t)(F + f) * FO + o];
        const float wd = wt - wb;
#pragma unroll
        for (int i = 0; i < RPT; ++i) {
            const float xv = xs[r0 + i * RS][f];
            accA[i] = fmaf(xv, wd, accA[i]);
            accB[i] = fmaf(xv, wb, accB[i]);
        }
    }
    const float bo = bias[o];
#pragma unroll
    for (int i = 0; i < RPT; ++i) {
        const size_t row = (size_t)(n0 + r0 + i * RS);
        A[row * FO + o]  = accA[i] + bo;
        Bm[row * FO + o] = accB[i];
    }
}

// ---------------------------------------------------------------------------
// Combine (float4): x_out = relu(A + max_k Bm[nbr])
// ---------------------------------------------------------------------------
template<int FO>
__global__ __launch_bounds__(256) void combine_kernel(const float* __restrict__ A,
                                                      const float* __restrict__ Bm,
                                                      const int* __restrict__ nbr,
                                                      float* __restrict__ xout) {
    constexpr int FO4 = FO / 4;
    const int idx = blockIdx.x * 256 + threadIdx.x;   // over N*FO4
    const int n  = idx / FO4;
    const int o4 = idx % FO4;
    const int* nb = nbr + (size_t)n * KNB;
    const float4* B4 = reinterpret_cast<const float4*>(Bm);
    float4 mx = make_float4(-FLT_MAX, -FLT_MAX, -FLT_MAX, -FLT_MAX);
#pragma unroll 8
    for (int k = 0; k < KNB; ++k) {
        const float4 v = B4[(size_t)nb[k] * FO4 + o4];
        mx.x = fmaxf(mx.x, v.x); mx.y = fmaxf(mx.y, v.y);
        mx.z = fmaxf(mx.z, v.z); mx.w = fmaxf(mx.w, v.w);
    }
    const float4 a = reinterpret_cast<const float4*>(A)[idx];
    float4 rr;
    rr.x = fmaxf(a.x + mx.x, 0.f);
    rr.y = fmaxf(a.y + mx.y, 0.f);
    rr.z = fmaxf(a.z + mx.z, 0.f);
    rr.w = fmaxf(a.w + mx.w, 0.f);
    reinterpret_cast<float4*>(xout)[idx] = rr;
}

// ---------------------------------------------------------------------------
// Classifier + loss
// ---------------------------------------------------------------------------
__global__ __launch_bounds__(256) void classifier_kernel(const float* __restrict__ x,
                                                         const float* __restrict__ Wc,
                                                         const float* __restrict__ bc,
                                                         const int* __restrict__ target,
                                                         float* __restrict__ probs,
                                                         float* __restrict__ lossbuf) {
    const int tid = threadIdx.x;
    const int lane = tid & 63;
    const int n = blockIdx.x * 4 + (tid >> 6);
    const float* xr = x + (size_t)n * 256;
    float logit = -FLT_MAX;
    if (lane < NCLS) {
        float acc = bc[lane];
        for (int f = 0; f < 256; ++f)
            acc = fmaf(xr[f], Wc[f * NCLS + lane], acc);
        logit = acc;
    }
    float m = logit;
#pragma unroll
    for (int off = 32; off; off >>= 1) m = fmaxf(m, __shfl_xor(m, off));
    const float e = (lane < NCLS) ? __expf(logit - m) : 0.f;
    float s = e;
#pragma unroll
    for (int off = 32; off; off >>= 1) s += __shfl_xor(s, off);
    if (lane < NCLS) probs[(size_t)n * NCLS + lane] = e / s;
    const float lt = __shfl(logit, target[n]);
    if (lane == 0) lossbuf[n] = logf(s) - (lt - m);
}

__global__ __launch_bounds__(256) void loss_reduce_kernel(const float* __restrict__ lossbuf,
                                                          float* __restrict__ out) {
    __shared__ float s[256];
    float acc = 0.f;
    for (int i = threadIdx.x; i < NPTS; i += 256) acc += lossbuf[i];
    s[threadIdx.x] = acc;
    __syncthreads();
    for (int off = 128; off; off >>= 1) {
        if (threadIdx.x < off) s[threadIdx.x] += s[threadIdx.x + off];
        __syncthreads();
    }
    if (threadIdx.x == 0) out[0] = s[0] / (float)NPTS;
}

extern "C" void kernel_launch(void* const* d_in, const int* in_sizes, int n_in,
                              void* d_out, int out_size, void* d_ws, size_t ws_size,
                              hipStream_t stream) {
    (void)in_sizes; (void)n_in; (void)out_size; (void)ws_size;
    const float* x_in   = (const float*)d_in[0];
    const int*   target = (const int*)d_in[2];
    const float* W1 = (const float*)d_in[3];
    const float* b1 = (const float*)d_in[4];
    const float* W2 = (const float*)d_in[5];
    const float* b2 = (const float*)d_in[6];
    const float* W3 = (const float*)d_in[7];
    const float* b3 = (const float*)d_in[8];
    const float* Wc = (const float*)d_in[9];
    const float* bc = (const float*)d_in[10];

    // proven-safe window [0, 50MB+64KB):
    //   X [0,16M) | A [16,32M) | Bm [32,48M) | nbr [48,50M) | lossbuf [50M,+64K)
    //   xT [32,40M) + qn [40M,+64K) alias dead-Bm during kNN phase
    char* ws = (char*)d_ws;
    float* X       = (float*)(ws);
    float* A       = (float*)(ws + (size_t)16 * 1024 * 1024);
    float* Bm      = (float*)(ws + (size_t)32 * 1024 * 1024);
    float* xT      = (float*)(ws + (size_t)32 * 1024 * 1024);
    float* qn      = (float*)(ws + (size_t)40 * 1024 * 1024);
    int*   nbr     = (int*)  (ws + (size_t)48 * 1024 * 1024);
    float* lossbuf = (float*)(ws + (size_t)50 * 1024 * 1024);

    float* outF  = (float*)d_out;
    float* probs = outF + 1;

    // ---- layer 1 (3 -> 64) ----
    xpose_kernel<3><<<NPTS / 256, 256, 0, stream>>>(x_in, xT, qn);
    knn_kernel<3><<<NPTS / RPB, 256, 0, stream>>>(x_in, xT, qn, nbr);
    edge_gemm_kernel<3, 64><<<NPTS / 16, 256, 0, stream>>>(x_in, W1, b1, A, Bm);
    combine_kernel<64><<<NPTS * 16 / 256, 256, 0, stream>>>(A, Bm, nbr, X);

    // ---- layer 2 (64 -> 128) ----
    xpose_kernel<64><<<NPTS / 256, 256, 0, stream>>>(X, xT, qn);
    knn_kernel<64><<<NPTS / RPB, 256, 0, stream>>>(X, xT, qn, nbr);
    edge_gemm_kernel<64, 128><<<NPTS / 16, 256, 0, stream>>>(X, W2, b2, A, Bm);
    combine_kernel<128><<<NPTS * 32 / 256, 256, 0, stream>>>(A, Bm, nbr, X);

    // ---- layer 3 (128 -> 256) ----
    xpose_kernel<128><<<NPTS / 256, 256, 0, stream>>>(X, xT, qn);
    knn_kernel<128><<<NPTS / RPB, 256, 0, stream>>>(X, xT, qn, nbr);
    edge_gemm_kernel<128, 256><<<NPTS / 16, 256, 0, stream>>>(X, W3, b3, A, Bm);
    combine_kernel<256><<<NPTS * 64 / 256, 256, 0, stream>>>(A, Bm, nbr, X);

    // ---- classifier + loss ----
    classifier_kernel<<<NPTS / 4, 256, 0, stream>>>(X, Wc, bc, target, probs, lossbuf);
    loss_reduce_kernel<<<1, 256, 0, stream>>>(lossbuf, outF);
}